// Round 3
// baseline (460.255 us; speedup 1.0000x reference)
//
#include <hip/hip_runtime.h>
#include <math.h>

#define NN 100000
#define F0 128
#define F1 16
#define F2 10
#define NBUCK 391   // ceil(NN / 256)
#define TILE 16384  // edges per binplace block
#define CAP 16384   // LDS staging capacity in k_bucket

__device__ inline void fma4(float4& a, float s, const float4& w) {
  a.x = fmaf(s, w.x, a.x);
  a.y = fmaf(s, w.y, a.y);
  a.z = fmaf(s, w.z, a.z);
  a.w = fmaf(s, w.w, a.w);
}

// ---- zero coarse bucket counters ----
__global__ void k_zero(int* __restrict__ bucket_cnt) {
  int i = blockIdx.x * blockDim.x + threadIdx.x;
  if (i < NBUCK) bucket_cnt[i] = 0;
}

__global__ __launch_bounds__(256) void k_bincount(const int* __restrict__ dst, int E,
                                                  int* __restrict__ bucket_cnt) {
  __shared__ int hist[NBUCK];
  int t = threadIdx.x;
  for (int i = t; i < NBUCK; i += 256) hist[i] = 0;
  __syncthreads();
  int per = (E + gridDim.x - 1) / gridDim.x;
  int e0 = blockIdx.x * per, e1 = min(E, e0 + per);
  for (int e = e0 + t; e < e1; e += 256)
    atomicAdd(&hist[__builtin_nontemporal_load(dst + e) >> 8], 1);
  __syncthreads();
  for (int i = t; i < NBUCK; i += 256)
    if (hist[i]) atomicAdd(&bucket_cnt[i], hist[i]);
}

__global__ void k_binscan(const int* __restrict__ bucket_cnt, int* __restrict__ bucket_base,
                          int* __restrict__ bucket_cur) {
  __shared__ int lds[512];
  int t = threadIdx.x;
  int v = (t < NBUCK) ? bucket_cnt[t] : 0;
  lds[t] = v;
  __syncthreads();
  for (int o = 1; o < 512; o <<= 1) {
    int add = (t >= o) ? lds[t - o] : 0;
    __syncthreads();
    lds[t] += add;
    __syncthreads();
  }
  if (t < NBUCK) {
    int excl = lds[t] - v;
    bucket_base[t] = excl;
    bucket_cur[t] = excl;
    if (t == NBUCK - 1) bucket_base[NBUCK] = lds[t];  // == E
  }
}

__global__ __launch_bounds__(256) void k_binplace(const int* __restrict__ src,
                                                  const int* __restrict__ dst, int E,
                                                  int* __restrict__ bucket_cur,
                                                  int* __restrict__ packed) {
  __shared__ int hbase[NBUCK];
  __shared__ int hcur[NBUCK];
  int t = threadIdx.x;
  int e0 = blockIdx.x * TILE, e1 = min(E, e0 + TILE);
  for (int i = t; i < NBUCK; i += 256) { hbase[i] = 0; hcur[i] = 0; }
  __syncthreads();
  for (int e = e0 + t; e < e1; e += 256)
    atomicAdd(&hbase[__builtin_nontemporal_load(dst + e) >> 8], 1);
  __syncthreads();
  for (int i = t; i < NBUCK; i += 256) {
    int c = hbase[i];
    hbase[i] = (c > 0) ? atomicAdd(&bucket_cur[i], c) : 0;
  }
  __syncthreads();
  for (int e = e0 + t; e < e1; e += 256) {
    int d = __builtin_nontemporal_load(dst + e);
    int s = __builtin_nontemporal_load(src + e);
    int bk = d >> 8;
    int pos = atomicAdd(&hcur[bk], 1);
    packed[hbase[bk] + pos] = (s << 8) | (d & 255);
  }
}

__global__ __launch_bounds__(256) void k_bucket(const int* __restrict__ packed,
                                                const int* __restrict__ bucket_base,
                                                int* __restrict__ row_start,
                                                float* __restrict__ dinv,
                                                int* __restrict__ col, int E) {
  __shared__ int stage[CAP];
  __shared__ int hist[256];
  __shared__ int off[256];
  __shared__ int cur[256];
  int b = blockIdx.x, t = threadIdx.x;
  int base = bucket_base[b];
  int cnt = bucket_base[b + 1] - base;
  hist[t] = 0;
  bool staged = (cnt <= CAP);
  if (staged)
    for (int i = t; i < cnt; i += 256) stage[i] = __builtin_nontemporal_load(packed + base + i);
  __syncthreads();
  if (staged) {
    for (int i = t; i < cnt; i += 256) atomicAdd(&hist[stage[i] & 255], 1);
  } else {
    for (int i = t; i < cnt; i += 256) atomicAdd(&hist[packed[base + i] & 255], 1);
  }
  __syncthreads();
  int v = hist[t];
  off[t] = v;
  __syncthreads();
  for (int o = 1; o < 256; o <<= 1) {
    int add = (t >= o) ? off[t - o] : 0;
    __syncthreads();
    off[t] += add;
    __syncthreads();
  }
  int excl = off[t] - v;
  cur[t] = excl;
  int d = b * 256 + t;
  if (d < NN) {
    row_start[d] = base + excl;
    dinv[d] = rsqrtf((float)(v + 1));  // +1 self-loop
  }
  if (b == 0 && t == 0) row_start[NN] = E;
  __syncthreads();
  if (staged) {
    for (int i = t; i < cnt; i += 256) {
      int p = stage[i];
      int pos = atomicAdd(&cur[p & 255], 1);
      col[base + pos] = p >> 8;
    }
  } else {
    for (int i = t; i < cnt; i += 256) {
      int p = packed[base + i];
      int pos = atomicAdd(&cur[p & 255], 1);
      col[base + pos] = p >> 8;
    }
  }
}

// ---- h1 = x @ W1, written as two [N][8] half-tables ----
__global__ __launch_bounds__(256) void k_lin1(const float* __restrict__ x,
                                              const float* __restrict__ W1,
                                              float* __restrict__ h1a,
                                              float* __restrict__ h1b) {
  __shared__ float4 wl[F0 * 4];  // [k][jq], 8 KB
  int t = threadIdx.x;
  for (int i = t; i < F0 * 4; i += 256) wl[i] = ((const float4*)W1)[i];
  __syncthreads();
  int row0 = (blockIdx.x * 256 + t) * 4;
  if (row0 >= NN) return;  // N % 4 == 0
  float4 acc[4][4];
#pragma unroll
  for (int r = 0; r < 4; r++)
#pragma unroll
    for (int j = 0; j < 4; j++) acc[r][j] = make_float4(0.f, 0.f, 0.f, 0.f);
  const float4* xr0 = (const float4*)(x + (size_t)(row0 + 0) * F0);
  const float4* xr1 = (const float4*)(x + (size_t)(row0 + 1) * F0);
  const float4* xr2 = (const float4*)(x + (size_t)(row0 + 2) * F0);
  const float4* xr3 = (const float4*)(x + (size_t)(row0 + 3) * F0);
  for (int k4 = 0; k4 < F0 / 4; k4++) {
    float4 xv[4];
    xv[0] = xr0[k4]; xv[1] = xr1[k4]; xv[2] = xr2[k4]; xv[3] = xr3[k4];
#pragma unroll
    for (int kk = 0; kk < 4; kk++) {
      float4 w0 = wl[(k4 * 4 + kk) * 4 + 0];
      float4 w1 = wl[(k4 * 4 + kk) * 4 + 1];
      float4 w2 = wl[(k4 * 4 + kk) * 4 + 2];
      float4 w3 = wl[(k4 * 4 + kk) * 4 + 3];
#pragma unroll
      for (int r = 0; r < 4; r++) {
        float xs = kk == 0 ? xv[r].x : kk == 1 ? xv[r].y : kk == 2 ? xv[r].z : xv[r].w;
        fma4(acc[r][0], xs, w0);
        fma4(acc[r][1], xs, w1);
        fma4(acc[r][2], xs, w2);
        fma4(acc[r][3], xs, w3);
      }
    }
  }
#pragma unroll
  for (int r = 0; r < 4; r++) {
    float4* ha = (float4*)(h1a + (size_t)(row0 + r) * 8);
    float4* hb = (float4*)(h1b + (size_t)(row0 + r) * 8);
    ha[0] = acc[r][0]; ha[1] = acc[r][1];
    hb[0] = acc[r][2]; hb[1] = acc[r][3];
  }
}

// ---- half-table aggregation (+bias+ReLU); 2 threads/dst, table is [N][8] (3.2 MB, L2-fits) ----
__global__ __launch_bounds__(256) void k_agg1h(const float* __restrict__ tab,
                                               const int* __restrict__ row_start,
                                               const int* __restrict__ col,
                                               const float* __restrict__ dinv,
                                               const float* __restrict__ bias8,
                                               float* __restrict__ outt) {
  int t = blockIdx.x * blockDim.x + threadIdx.x;
  int d = t >> 1, q = t & 1;
  if (d >= NN) return;
  float dd = dinv[d];
  float sw = dd * dd;
  const float4* tab4 = (const float4*)tab;
  float4 acc = tab4[(size_t)d * 2 + q];
  acc.x *= sw; acc.y *= sw; acc.z *= sw; acc.w *= sw;
  int e = row_start[d], e1 = row_start[d + 1];
  for (; e + 1 < e1; e += 2) {
    int s0 = __builtin_nontemporal_load(col + e);
    int s1 = __builtin_nontemporal_load(col + e + 1);
    float w0 = dinv[s0] * dd, w1 = dinv[s1] * dd;
    float4 v0 = tab4[(size_t)s0 * 2 + q];
    float4 v1 = tab4[(size_t)s1 * 2 + q];
    fma4(acc, w0, v0);
    fma4(acc, w1, v1);
  }
  if (e < e1) {
    int s0 = __builtin_nontemporal_load(col + e);
    fma4(acc, dinv[s0] * dd, tab4[(size_t)s0 * 2 + q]);
  }
  float4 bb = ((const float4*)bias8)[q];
  acc.x = fmaxf(acc.x + bb.x, 0.f);
  acc.y = fmaxf(acc.y + bb.y, 0.f);
  acc.z = fmaxf(acc.z + bb.z, 0.f);
  acc.w = fmaxf(acc.w + bb.w, 0.f);
  ((float4*)outt)[(size_t)d * 2 + q] = acc;
}

// ---- h2 = h1r @ W2; h2a [N][8] cols 0-7, h2b [N][4] cols 8,9,pad ----
__global__ __launch_bounds__(256) void k_lin2(const float* __restrict__ h1ra,
                                              const float* __restrict__ h1rb,
                                              const float* __restrict__ W2,
                                              float* __restrict__ h2a,
                                              float* __restrict__ h2b) {
  __shared__ float4 wl[F1 * 3];  // [k][jq], jq2 = cols 8,9,0,0
  int t = threadIdx.x;
  if (t < F1 * 3) {
    int k = t / 3, jq = t % 3;
    float tmp[4];
#pragma unroll
    for (int c = 0; c < 4; c++) {
      int j = jq * 4 + c;
      tmp[c] = (j < F2) ? W2[k * F2 + j] : 0.f;
    }
    wl[t] = make_float4(tmp[0], tmp[1], tmp[2], tmp[3]);
  }
  __syncthreads();
  int row = blockIdx.x * blockDim.x + t;
  if (row >= NN) return;
  const float4* ra = (const float4*)(h1ra + (size_t)row * 8);
  const float4* rb = (const float4*)(h1rb + (size_t)row * 8);
  float4 hq[4] = {ra[0], ra[1], rb[0], rb[1]};  // k = 0..15
  float4 acc[3];
#pragma unroll
  for (int j = 0; j < 3; j++) acc[j] = make_float4(0.f, 0.f, 0.f, 0.f);
#pragma unroll
  for (int k4 = 0; k4 < 4; k4++) {
#pragma unroll
    for (int kk = 0; kk < 4; kk++) {
      int k = k4 * 4 + kk;
      float hs = kk == 0 ? hq[k4].x : kk == 1 ? hq[k4].y : kk == 2 ? hq[k4].z : hq[k4].w;
#pragma unroll
      for (int jq = 0; jq < 3; jq++) fma4(acc[jq], hs, wl[k * 3 + jq]);
    }
  }
  float4* oa = (float4*)(h2a + (size_t)row * 8);
  oa[0] = acc[0]; oa[1] = acc[1];
  ((float4*)(h2b + (size_t)row * 4))[0] = acc[2];
}

// ---- layer-2 half aggregations (no bias; finisher applies it) ----
__global__ __launch_bounds__(256) void k_agg2a(const float* __restrict__ tab,
                                               const int* __restrict__ row_start,
                                               const int* __restrict__ col,
                                               const float* __restrict__ dinv,
                                               float* __restrict__ outt) {
  int t = blockIdx.x * blockDim.x + threadIdx.x;
  int d = t >> 1, q = t & 1;
  if (d >= NN) return;
  float dd = dinv[d];
  float sw = dd * dd;
  const float4* tab4 = (const float4*)tab;
  float4 acc = tab4[(size_t)d * 2 + q];
  acc.x *= sw; acc.y *= sw; acc.z *= sw; acc.w *= sw;
  int e = row_start[d], e1 = row_start[d + 1];
  for (; e + 1 < e1; e += 2) {
    int s0 = __builtin_nontemporal_load(col + e);
    int s1 = __builtin_nontemporal_load(col + e + 1);
    float w0 = dinv[s0] * dd, w1 = dinv[s1] * dd;
    float4 v0 = tab4[(size_t)s0 * 2 + q];
    float4 v1 = tab4[(size_t)s1 * 2 + q];
    fma4(acc, w0, v0);
    fma4(acc, w1, v1);
  }
  if (e < e1) {
    int s0 = __builtin_nontemporal_load(col + e);
    fma4(acc, dinv[s0] * dd, tab4[(size_t)s0 * 2 + q]);
  }
  ((float4*)outt)[(size_t)d * 2 + q] = acc;
}

__global__ __launch_bounds__(256) void k_agg2b(const float* __restrict__ tab,
                                               const int* __restrict__ row_start,
                                               const int* __restrict__ col,
                                               const float* __restrict__ dinv,
                                               float* __restrict__ outt) {
  int d = blockIdx.x * blockDim.x + threadIdx.x;
  if (d >= NN) return;
  float dd = dinv[d];
  float sw = dd * dd;
  const float4* tab4 = (const float4*)tab;
  float4 acc = tab4[d];
  acc.x *= sw; acc.y *= sw; acc.z *= sw; acc.w *= sw;
  int e = row_start[d], e1 = row_start[d + 1];
  for (; e + 1 < e1; e += 2) {
    int s0 = __builtin_nontemporal_load(col + e);
    int s1 = __builtin_nontemporal_load(col + e + 1);
    float w0 = dinv[s0] * dd, w1 = dinv[s1] * dd;
    float4 v0 = tab4[s0];
    float4 v1 = tab4[s1];
    fma4(acc, w0, v0);
    fma4(acc, w1, v1);
  }
  if (e < e1) {
    int s0 = __builtin_nontemporal_load(col + e);
    fma4(acc, dinv[s0] * dd, tab4[s0]);
  }
  ((float4*)outt)[d] = acc;
}

// ---- bias + log_softmax finisher ----
__global__ __launch_bounds__(256) void k_smax(const float* __restrict__ o2a,
                                              const float* __restrict__ o2b,
                                              const float* __restrict__ b2,
                                              float* __restrict__ out) {
  int d = blockIdx.x * blockDim.x + threadIdx.x;
  if (d >= NN) return;
  const float4* pa = (const float4*)(o2a + (size_t)d * 8);
  float4 a0 = pa[0], a1 = pa[1];
  float4 a2 = ((const float4*)(o2b + (size_t)d * 4))[0];
  float v[10];
  v[0] = a0.x; v[1] = a0.y; v[2] = a0.z; v[3] = a0.w;
  v[4] = a1.x; v[5] = a1.y; v[6] = a1.z; v[7] = a1.w;
  v[8] = a2.x; v[9] = a2.y;
#pragma unroll
  for (int j = 0; j < F2; j++) v[j] += b2[j];
  float m = v[0];
#pragma unroll
  for (int j = 1; j < F2; j++) m = fmaxf(m, v[j]);
  float sum = 0.f;
#pragma unroll
  for (int j = 0; j < F2; j++) sum += expf(v[j] - m);
  float lse = m + logf(sum);
  float* o = out + (size_t)d * F2;
#pragma unroll
  for (int j = 0; j < F2; j++) o[j] = v[j] - lse;
}

extern "C" void kernel_launch(void* const* d_in, const int* in_sizes, int n_in,
                              void* d_out, int out_size, void* d_ws, size_t ws_size,
                              hipStream_t stream) {
  const float* x  = (const float*)d_in[0];
  const int*   ei = (const int*)d_in[1];
  const float* W1 = (const float*)d_in[2];
  const float* b1 = (const float*)d_in[3];
  const float* W2 = (const float*)d_in[4];
  const float* b2 = (const float*)d_in[5];
  float* out = (float*)d_out;
  int E = in_sizes[1] / 2;
  const int* src = ei;
  const int* dst = ei + E;

  char* p = (char*)d_ws;
  auto alloc = [&](size_t bytes) {
    char* r = p;
    p += (bytes + 255) & ~(size_t)255;
    return r;
  };
  size_t halfT = (size_t)NN * 8 * 4;   // 3.2 MB
  size_t quadT = (size_t)NN * 4 * 4;   // 1.6 MB
  float* dinv        = (float*)alloc((size_t)NN * 4);
  int*   row_start   = (int*)alloc((size_t)(NN + 1) * 4);
  int*   bucket_cnt  = (int*)alloc((size_t)NBUCK * 4);
  int*   bucket_base = (int*)alloc((size_t)(NBUCK + 1) * 4);
  int*   bucket_cur  = (int*)alloc((size_t)NBUCK * 4);
  int*   col         = (int*)alloc((size_t)E * 4);
  // regionA: packed (E ints) dead after k_bucket; then h1a,h1b,h2a,h2b overlay it.
  size_t needA = halfT * 3 + quadT;  // 11.2 MB
  size_t regA = (size_t)E * 4;
  char*  A = (char*)alloc(regA > needA ? regA : needA);
  int*   packed = (int*)A;
  float* h1a = (float*)A;
  float* h1b = (float*)(A + halfT);
  float* h2a = (float*)(A + 2 * halfT);
  float* h2b = (float*)(A + 3 * halfT);
  // regionB: h1ra,h1rb dead after k_lin2; o2a,o2b overlay them.
  char*  B = (char*)alloc(2 * halfT);
  float* h1ra = (float*)B;
  float* h1rb = (float*)(B + halfT);
  float* o2a  = (float*)B;
  float* o2b  = (float*)(B + halfT);

  int nblkN  = (NN + 255) / 256;        // 391
  int nblk2N = (2 * NN + 255) / 256;    // 782
  int nblk_place = (E + TILE - 1) / TILE;
  hipLaunchKernelGGL(k_zero, dim3(2), dim3(256), 0, stream, bucket_cnt);
  hipLaunchKernelGGL(k_bincount, dim3(256), dim3(256), 0, stream, dst, E, bucket_cnt);
  hipLaunchKernelGGL(k_binscan, dim3(1), dim3(512), 0, stream, bucket_cnt, bucket_base, bucket_cur);
  hipLaunchKernelGGL(k_binplace, dim3(nblk_place), dim3(256), 0, stream, src, dst, E, bucket_cur, packed);
  hipLaunchKernelGGL(k_bucket, dim3(NBUCK), dim3(256), 0, stream, packed, bucket_base, row_start, dinv, col, E);
  hipLaunchKernelGGL(k_lin1, dim3((NN / 4 + 255) / 256), dim3(256), 0, stream, x, W1, h1a, h1b);
  hipLaunchKernelGGL(k_agg1h, dim3(nblk2N), dim3(256), 0, stream, h1a, row_start, col, dinv, b1, h1ra);
  hipLaunchKernelGGL(k_agg1h, dim3(nblk2N), dim3(256), 0, stream, h1b, row_start, col, dinv, b1 + 8, h1rb);
  hipLaunchKernelGGL(k_lin2, dim3(nblkN), dim3(256), 0, stream, h1ra, h1rb, W2, h2a, h2b);
  hipLaunchKernelGGL(k_agg2a, dim3(nblk2N), dim3(256), 0, stream, h2a, row_start, col, dinv, o2a);
  hipLaunchKernelGGL(k_agg2b, dim3(nblkN), dim3(256), 0, stream, h2b, row_start, col, dinv, o2b);
  hipLaunchKernelGGL(k_smax, dim3(nblkN), dim3(256), 0, stream, o2a, o2b, b2, out);
}

// Round 4
// 358.848 us; speedup vs baseline: 1.2826x; 1.2826x over previous
//
#include <hip/hip_runtime.h>
#include <hip/hip_fp16.h>
#include <math.h>

#define NN 100000
#define F0 128
#define F1 16
#define F2 10
#define NBUCK 391   // ceil(NN / 256)
#define TILE 16384  // edges per binplace block
#define CAP 16384   // LDS staging capacity in k_bucket

__device__ inline void fma4(float4& a, float s, const float4& w) {
  a.x = fmaf(s, w.x, a.x);
  a.y = fmaf(s, w.y, a.y);
  a.z = fmaf(s, w.z, a.z);
  a.w = fmaf(s, w.w, a.w);
}

__device__ inline unsigned pk2(float a, float b) {
  __half ha = __float2half(a), hb = __float2half(b);
  return (unsigned)__half_as_ushort(ha) | ((unsigned)__half_as_ushort(hb) << 16);
}

__device__ inline float2 up2(unsigned u) {
  __half2 h;
  *(unsigned*)&h = u;
  return __half22float2(h);
}

// ==================== CSR build (two-level counting sort) ====================
__global__ void k_zero(int* __restrict__ bucket_cnt) {
  int i = blockIdx.x * blockDim.x + threadIdx.x;
  if (i < NBUCK) bucket_cnt[i] = 0;
}

__global__ __launch_bounds__(256) void k_bincount(const int* __restrict__ dst, int E,
                                                  int* __restrict__ bucket_cnt) {
  __shared__ int hist[NBUCK];
  int t = threadIdx.x;
  for (int i = t; i < NBUCK; i += 256) hist[i] = 0;
  __syncthreads();
  int per = (E + gridDim.x - 1) / gridDim.x;
  int e0 = blockIdx.x * per, e1 = min(E, e0 + per);
  for (int e = e0 + t; e < e1; e += 256)
    atomicAdd(&hist[__builtin_nontemporal_load(dst + e) >> 8], 1);
  __syncthreads();
  for (int i = t; i < NBUCK; i += 256)
    if (hist[i]) atomicAdd(&bucket_cnt[i], hist[i]);
}

__global__ void k_binscan(const int* __restrict__ bucket_cnt, int* __restrict__ bucket_base,
                          int* __restrict__ bucket_cur) {
  __shared__ int lds[512];
  int t = threadIdx.x;
  int v = (t < NBUCK) ? bucket_cnt[t] : 0;
  lds[t] = v;
  __syncthreads();
  for (int o = 1; o < 512; o <<= 1) {
    int add = (t >= o) ? lds[t - o] : 0;
    __syncthreads();
    lds[t] += add;
    __syncthreads();
  }
  if (t < NBUCK) {
    int excl = lds[t] - v;
    bucket_base[t] = excl;
    bucket_cur[t] = excl;
    if (t == NBUCK - 1) bucket_base[NBUCK] = lds[t];  // == E
  }
}

__global__ __launch_bounds__(256) void k_binplace(const int* __restrict__ src,
                                                  const int* __restrict__ dst, int E,
                                                  int* __restrict__ bucket_cur,
                                                  int* __restrict__ packed) {
  __shared__ int hbase[NBUCK];
  __shared__ int hcur[NBUCK];
  int t = threadIdx.x;
  int e0 = blockIdx.x * TILE, e1 = min(E, e0 + TILE);
  for (int i = t; i < NBUCK; i += 256) { hbase[i] = 0; hcur[i] = 0; }
  __syncthreads();
  for (int e = e0 + t; e < e1; e += 256)
    atomicAdd(&hbase[__builtin_nontemporal_load(dst + e) >> 8], 1);
  __syncthreads();
  for (int i = t; i < NBUCK; i += 256) {
    int c = hbase[i];
    hbase[i] = (c > 0) ? atomicAdd(&bucket_cur[i], c) : 0;
  }
  __syncthreads();
  for (int e = e0 + t; e < e1; e += 256) {
    int d = __builtin_nontemporal_load(dst + e);
    int s = __builtin_nontemporal_load(src + e);
    int bk = d >> 8;
    int pos = atomicAdd(&hcur[bk], 1);
    __builtin_nontemporal_store((s << 8) | (d & 255), packed + hbase[bk] + pos);
  }
}

__global__ __launch_bounds__(256) void k_bucket(const int* __restrict__ packed,
                                                const int* __restrict__ bucket_base,
                                                int* __restrict__ row_start,
                                                float* __restrict__ dinv,
                                                int* __restrict__ col, int E) {
  __shared__ int stage[CAP];
  __shared__ int hist[256];
  __shared__ int off[256];
  __shared__ int cur[256];
  int b = blockIdx.x, t = threadIdx.x;
  int base = bucket_base[b];
  int cnt = bucket_base[b + 1] - base;
  hist[t] = 0;
  bool staged = (cnt <= CAP);
  if (staged)
    for (int i = t; i < cnt; i += 256) stage[i] = __builtin_nontemporal_load(packed + base + i);
  __syncthreads();
  if (staged) {
    for (int i = t; i < cnt; i += 256) atomicAdd(&hist[stage[i] & 255], 1);
  } else {
    for (int i = t; i < cnt; i += 256) atomicAdd(&hist[packed[base + i] & 255], 1);
  }
  __syncthreads();
  int v = hist[t];
  off[t] = v;
  __syncthreads();
  for (int o = 1; o < 256; o <<= 1) {
    int add = (t >= o) ? off[t - o] : 0;
    __syncthreads();
    off[t] += add;
    __syncthreads();
  }
  int excl = off[t] - v;
  cur[t] = excl;
  int d = b * 256 + t;
  if (d < NN) {
    row_start[d] = base + excl;
    dinv[d] = rsqrtf((float)(v + 1));  // +1 self-loop
  }
  if (b == 0 && t == 0) row_start[NN] = E;
  __syncthreads();
  if (staged) {
    for (int i = t; i < cnt; i += 256) {
      int p = stage[i];
      int pos = atomicAdd(&cur[p & 255], 1);
      __builtin_nontemporal_store(p >> 8, col + base + pos);
    }
  } else {
    for (int i = t; i < cnt; i += 256) {
      int p = packed[base + i];
      int pos = atomicAdd(&cur[p & 255], 1);
      __builtin_nontemporal_store(p >> 8, col + base + pos);
    }
  }
}

// ==================== tab1 = fp16(dinv * (x @ W1)), [N][16] fp16 (3.2 MB) ====================
__global__ __launch_bounds__(256) void k_lin1(const float* __restrict__ x,
                                              const float* __restrict__ W1,
                                              const float* __restrict__ dinv,
                                              unsigned* __restrict__ tab1) {
  __shared__ float4 wl[F0 * 4];  // [k][jq], 8 KB
  int t = threadIdx.x;
  for (int i = t; i < F0 * 4; i += 256) wl[i] = ((const float4*)W1)[i];
  __syncthreads();
  int row0 = (blockIdx.x * 256 + t) * 4;
  if (row0 >= NN) return;  // N % 4 == 0
  float4 acc[4][4];
#pragma unroll
  for (int r = 0; r < 4; r++)
#pragma unroll
    for (int j = 0; j < 4; j++) acc[r][j] = make_float4(0.f, 0.f, 0.f, 0.f);
  const float4* xr0 = (const float4*)(x + (size_t)(row0 + 0) * F0);
  const float4* xr1 = (const float4*)(x + (size_t)(row0 + 1) * F0);
  const float4* xr2 = (const float4*)(x + (size_t)(row0 + 2) * F0);
  const float4* xr3 = (const float4*)(x + (size_t)(row0 + 3) * F0);
  for (int k4 = 0; k4 < F0 / 4; k4++) {
    float4 xv[4];
    xv[0] = xr0[k4]; xv[1] = xr1[k4]; xv[2] = xr2[k4]; xv[3] = xr3[k4];
#pragma unroll
    for (int kk = 0; kk < 4; kk++) {
      float4 w0 = wl[(k4 * 4 + kk) * 4 + 0];
      float4 w1 = wl[(k4 * 4 + kk) * 4 + 1];
      float4 w2 = wl[(k4 * 4 + kk) * 4 + 2];
      float4 w3 = wl[(k4 * 4 + kk) * 4 + 3];
#pragma unroll
      for (int r = 0; r < 4; r++) {
        float xs = kk == 0 ? xv[r].x : kk == 1 ? xv[r].y : kk == 2 ? xv[r].z : xv[r].w;
        fma4(acc[r][0], xs, w0);
        fma4(acc[r][1], xs, w1);
        fma4(acc[r][2], xs, w2);
        fma4(acc[r][3], xs, w3);
      }
    }
  }
#pragma unroll
  for (int r = 0; r < 4; r++) {
    float dd = dinv[row0 + r];
    float4 a0 = acc[r][0], a1 = acc[r][1], a2 = acc[r][2], a3 = acc[r][3];
    uint4 o0, o1;
    o0.x = pk2(dd * a0.x, dd * a0.y);
    o0.y = pk2(dd * a0.z, dd * a0.w);
    o0.z = pk2(dd * a1.x, dd * a1.y);
    o0.w = pk2(dd * a1.z, dd * a1.w);
    o1.x = pk2(dd * a2.x, dd * a2.y);
    o1.y = pk2(dd * a2.z, dd * a2.w);
    o1.z = pk2(dd * a3.x, dd * a3.y);
    o1.w = pk2(dd * a3.z, dd * a3.w);
    uint4* orow = (uint4*)(tab1 + (size_t)(row0 + r) * 8);
    orow[0] = o0;
    orow[1] = o1;
  }
}

// ==================== agg1 (+bias+ReLU) fused with lin2; 2 threads/dst ====================
// out[d] = dinv[d] * (tab1[d] + sum_e tab1[col[e]]); tab rows pre-scaled by dinv[src].
// Then h1r = relu(out + b1); partial W2 products exchanged via shfl_xor(1);
// tab2[d] = fp16(dinv[d] * (h1r @ W2)), [N][16] fp16 rows (cols 10-15 unused).
__global__ __launch_bounds__(256) void k_agg1(const uint4* __restrict__ tab1,
                                              const int* __restrict__ row_start,
                                              const int* __restrict__ col,
                                              const float* __restrict__ dinv,
                                              const float* __restrict__ b1,
                                              const float* __restrict__ W2g,
                                              unsigned* __restrict__ tab2) {
  __shared__ float w2[F1][F2];
  __shared__ float b1l[F1];
  int t = threadIdx.x;
  if (t < F1 * F2) w2[t / F2][t % F2] = W2g[t];
  if (t < F1) b1l[t] = b1[t];
  __syncthreads();
  int g = blockIdx.x * 256 + t;
  int d = g >> 1, q = g & 1;
  if (d >= NN) return;
  float a[8] = {0, 0, 0, 0, 0, 0, 0, 0};
  auto addv = [&](uint4 v) {
    float2 f0 = up2(v.x), f1 = up2(v.y), f2 = up2(v.z), f3 = up2(v.w);
    a[0] += f0.x; a[1] += f0.y; a[2] += f1.x; a[3] += f1.y;
    a[4] += f2.x; a[5] += f2.y; a[6] += f3.x; a[7] += f3.y;
  };
  addv(tab1[2 * d + q]);  // self-loop row
  int e = row_start[d], e1 = row_start[d + 1];
  for (; e + 1 < e1; e += 2) {
    int s0 = __builtin_nontemporal_load(col + e);
    int s1 = __builtin_nontemporal_load(col + e + 1);
    uint4 v0 = tab1[2 * s0 + q];
    uint4 v1 = tab1[2 * s1 + q];
    addv(v0);
    addv(v1);
  }
  if (e < e1) addv(tab1[2 * __builtin_nontemporal_load(col + e) + q]);
  float dd = dinv[d];
  float h[8];
#pragma unroll
  for (int j = 0; j < 8; j++) h[j] = fmaxf(fmaf(dd, a[j], b1l[q * 8 + j]), 0.f);
  float p[F2];
#pragma unroll
  for (int j = 0; j < F2; j++) {
    float s = 0.f;
#pragma unroll
    for (int kk = 0; kk < 8; kk++) s = fmaf(h[kk], w2[q * 8 + kk][j], s);
    p[j] = s;
  }
#pragma unroll
  for (int j = 0; j < F2; j++) p[j] += __shfl_xor(p[j], 1);
  if (q == 0) {
    uint4 o;
    o.x = pk2(dd * p[0], dd * p[1]);
    o.y = pk2(dd * p[2], dd * p[3]);
    o.z = pk2(dd * p[4], dd * p[5]);
    o.w = pk2(dd * p[6], dd * p[7]);
    *(uint4*)(tab2 + (size_t)d * 8) = o;
  } else {
    tab2[(size_t)d * 8 + 4] = pk2(dd * p[8], dd * p[9]);
  }
}

// ==================== agg2 + bias + log_softmax; 1 thread/dst ====================
__global__ __launch_bounds__(256) void k_agg2(const unsigned* __restrict__ tab2,
                                              const int* __restrict__ row_start,
                                              const int* __restrict__ col,
                                              const float* __restrict__ dinv,
                                              const float* __restrict__ b2,
                                              float* __restrict__ out) {
  __shared__ float b2l[F2];
  int t = threadIdx.x;
  if (t < F2) b2l[t] = b2[t];
  __syncthreads();
  int d = blockIdx.x * 256 + t;
  if (d >= NN) return;
  float a[10] = {0, 0, 0, 0, 0, 0, 0, 0, 0, 0};
  auto addv = [&](int s) {
    const uint4 v = *(const uint4*)(tab2 + (size_t)s * 8);
    unsigned w = tab2[(size_t)s * 8 + 4];
    float2 f0 = up2(v.x), f1 = up2(v.y), f2 = up2(v.z), f3 = up2(v.w), f4 = up2(w);
    a[0] += f0.x; a[1] += f0.y; a[2] += f1.x; a[3] += f1.y;
    a[4] += f2.x; a[5] += f2.y; a[6] += f3.x; a[7] += f3.y;
    a[8] += f4.x; a[9] += f4.y;
  };
  addv(d);  // self-loop
  int e = row_start[d], e1 = row_start[d + 1];
  for (; e + 1 < e1; e += 2) {
    int s0 = __builtin_nontemporal_load(col + e);
    int s1 = __builtin_nontemporal_load(col + e + 1);
    addv(s0);
    addv(s1);
  }
  if (e < e1) addv(__builtin_nontemporal_load(col + e));
  float dd = dinv[d];
  float v[10];
#pragma unroll
  for (int j = 0; j < F2; j++) v[j] = fmaf(dd, a[j], b2l[j]);
  float m = v[0];
#pragma unroll
  for (int j = 1; j < F2; j++) m = fmaxf(m, v[j]);
  float sum = 0.f;
#pragma unroll
  for (int j = 0; j < F2; j++) sum += expf(v[j] - m);
  float lse = m + logf(sum);
  float2* o = (float2*)(out + (size_t)d * F2);
#pragma unroll
  for (int j = 0; j < 5; j++) o[j] = make_float2(v[2 * j] - lse, v[2 * j + 1] - lse);
}

extern "C" void kernel_launch(void* const* d_in, const int* in_sizes, int n_in,
                              void* d_out, int out_size, void* d_ws, size_t ws_size,
                              hipStream_t stream) {
  const float* x  = (const float*)d_in[0];
  const int*   ei = (const int*)d_in[1];
  const float* W1 = (const float*)d_in[2];
  const float* b1 = (const float*)d_in[3];
  const float* W2 = (const float*)d_in[4];
  const float* b2 = (const float*)d_in[5];
  float* out = (float*)d_out;
  int E = in_sizes[1] / 2;
  const int* src = ei;
  const int* dst = ei + E;

  char* p = (char*)d_ws;
  auto alloc = [&](size_t bytes) {
    char* r = p;
    p += (bytes + 255) & ~(size_t)255;
    return r;
  };
  size_t tabsz = (size_t)NN * 8 * 4;  // 3.2 MB ([N][16] fp16 = [N][8] uints)
  float* dinv        = (float*)alloc((size_t)NN * 4);
  int*   row_start   = (int*)alloc((size_t)(NN + 1) * 4);
  int*   bucket_cnt  = (int*)alloc((size_t)NBUCK * 4);
  int*   bucket_base = (int*)alloc((size_t)(NBUCK + 1) * 4);
  int*   bucket_cur  = (int*)alloc((size_t)NBUCK * 4);
  int*   col         = (int*)alloc((size_t)E * 4);
  // regionA: packed (E ints, 12.8 MB) dead after k_bucket; tab1+tab2 (6.4 MB) overlay it.
  size_t needA = tabsz * 2;
  size_t regA = (size_t)E * 4;
  char*  A = (char*)alloc(regA > needA ? regA : needA);
  int*      packed = (int*)A;
  unsigned* tab1 = (unsigned*)A;
  unsigned* tab2 = (unsigned*)(A + tabsz);

  int nblkN  = (NN + 255) / 256;        // 391
  int nblk2N = (2 * NN + 255) / 256;    // 782
  int nblk_place = (E + TILE - 1) / TILE;
  hipLaunchKernelGGL(k_zero, dim3(2), dim3(256), 0, stream, bucket_cnt);
  hipLaunchKernelGGL(k_bincount, dim3(256), dim3(256), 0, stream, dst, E, bucket_cnt);
  hipLaunchKernelGGL(k_binscan, dim3(1), dim3(512), 0, stream, bucket_cnt, bucket_base, bucket_cur);
  hipLaunchKernelGGL(k_binplace, dim3(nblk_place), dim3(256), 0, stream, src, dst, E, bucket_cur, packed);
  hipLaunchKernelGGL(k_bucket, dim3(NBUCK), dim3(256), 0, stream, packed, bucket_base, row_start, dinv, col, E);
  hipLaunchKernelGGL(k_lin1, dim3((NN / 4 + 255) / 256), dim3(256), 0, stream, x, W1, dinv, tab1);
  hipLaunchKernelGGL(k_agg1, dim3(nblk2N), dim3(256), 0, stream,
                     (const uint4*)tab1, row_start, col, dinv, b1, W2, tab2);
  hipLaunchKernelGGL(k_agg2, dim3(nblkN), dim3(256), 0, stream, tab2, row_start, col, dinv, b2, out);
}

// Round 5
// 244.164 us; speedup vs baseline: 1.8850x; 1.4697x over previous
//
#include <hip/hip_runtime.h>
#include <hip/hip_fp16.h>
#include <math.h>

#define NN 100000
#define F0 128
#define F1 16
#define F2 10
#define NBUCK 391   // ceil(NN / 256)
#define TILE 16384  // edges per binplace block
#define CAP 16384   // LDS staging capacity in k_bucket
#define BPT 512     // binplace threads

__device__ inline void fma4(float4& a, float s, const float4& w) {
  a.x = fmaf(s, w.x, a.x);
  a.y = fmaf(s, w.y, a.y);
  a.z = fmaf(s, w.z, a.z);
  a.w = fmaf(s, w.w, a.w);
}

__device__ inline unsigned pk2(float a, float b) {
  __half ha = __float2half(a), hb = __float2half(b);
  return (unsigned)__half_as_ushort(ha) | ((unsigned)__half_as_ushort(hb) << 16);
}

__device__ inline float2 up2(unsigned u) {
  __half2 h;
  *(unsigned*)&h = u;
  return __half22float2(h);
}

// ==================== CSR build (two-level counting sort) ====================
__global__ void k_zero(int* __restrict__ bucket_cnt) {
  int i = blockIdx.x * blockDim.x + threadIdx.x;
  if (i < NBUCK) bucket_cnt[i] = 0;
}

__global__ __launch_bounds__(256) void k_bincount(const int* __restrict__ dst, int E,
                                                  int* __restrict__ bucket_cnt) {
  __shared__ int hist[NBUCK];
  int t = threadIdx.x;
  for (int i = t; i < NBUCK; i += 256) hist[i] = 0;
  __syncthreads();
  int per = (E + gridDim.x - 1) / gridDim.x;
  int e0 = blockIdx.x * per, e1 = min(E, e0 + per);
  for (int e = e0 + t; e < e1; e += 256)
    atomicAdd(&hist[__builtin_nontemporal_load(dst + e) >> 8], 1);
  __syncthreads();
  for (int i = t; i < NBUCK; i += 256)
    if (hist[i]) atomicAdd(&bucket_cnt[i], hist[i]);
}

__global__ void k_binscan(const int* __restrict__ bucket_cnt, int* __restrict__ bucket_base,
                          int* __restrict__ bucket_cur) {
  __shared__ int lds[512];
  int t = threadIdx.x;
  int v = (t < NBUCK) ? bucket_cnt[t] : 0;
  lds[t] = v;
  __syncthreads();
  for (int o = 1; o < 512; o <<= 1) {
    int add = (t >= o) ? lds[t - o] : 0;
    __syncthreads();
    lds[t] += add;
    __syncthreads();
  }
  if (t < NBUCK) {
    int excl = lds[t] - v;
    bucket_base[t] = excl;
    bucket_cur[t] = excl;
    if (t == NBUCK - 1) bucket_base[NBUCK] = lds[t];  // == E
  }
}

// LDS-reorder binplace: tile -> LDS (sorted by bucket) -> contiguous run copies.
__global__ __launch_bounds__(BPT) void k_binplace(const int* __restrict__ src,
                                                  const int* __restrict__ dst, int E,
                                                  int* __restrict__ bucket_cur,
                                                  int* __restrict__ packed) {
  __shared__ int cnt[NBUCK];    // counts -> cursor
  __shared__ int loff[NBUCK];   // local exclusive offsets
  __shared__ int gbase[NBUCK];  // global base of this block's run per bucket
  __shared__ int part[256];     // scan partials
  __shared__ int stage[TILE];   // 64 KB reorder buffer
  int t = threadIdx.x;
  int e0 = blockIdx.x * TILE, e1 = min(E, e0 + TILE);
  int total = e1 - e0;
  for (int i = t; i < NBUCK; i += BPT) cnt[i] = 0;
  __syncthreads();
  for (int e = e0 + t; e < e1; e += BPT)
    atomicAdd(&cnt[__builtin_nontemporal_load(dst + e) >> 8], 1);
  __syncthreads();
  // reserve global space per bucket
  for (int i = t; i < NBUCK; i += BPT) {
    int c = cnt[i];
    gbase[i] = c ? atomicAdd(&bucket_cur[i], c) : 0;
  }
  // block scan of cnt -> loff (256 owners x 2 entries)
  if (t < 256) {
    int i0 = 2 * t, i1 = 2 * t + 1;
    int c0 = (i0 < NBUCK) ? cnt[i0] : 0;
    int c1 = (i1 < NBUCK) ? cnt[i1] : 0;
    part[t] = c0 + c1;
  }
  __syncthreads();
  for (int o = 1; o < 256; o <<= 1) {
    int add = 0;
    if (t < 256 && t >= o) add = part[t - o];
    __syncthreads();
    if (t < 256) part[t] += add;
    __syncthreads();
  }
  if (t < 256) {
    int i0 = 2 * t, i1 = 2 * t + 1;
    int c0 = (i0 < NBUCK) ? cnt[i0] : 0;
    int c1 = (i1 < NBUCK) ? cnt[i1] : 0;
    int excl = part[t] - c0 - c1;
    if (i0 < NBUCK) loff[i0] = excl;
    if (i1 < NBUCK) loff[i1] = excl + c0;
  }
  __syncthreads();
  for (int i = t; i < NBUCK; i += BPT) cnt[i] = loff[i];  // cursor
  __syncthreads();
  // scatter tile into LDS, sorted by bucket
  for (int e = e0 + t; e < e1; e += BPT) {
    int d = __builtin_nontemporal_load(dst + e);
    int s = __builtin_nontemporal_load(src + e);
    int bk = d >> 8;
    int pos = atomicAdd(&cnt[bk], 1);
    stage[pos] = (s << 8) | (d & 255);
  }
  __syncthreads();
  // contiguous run copy: one wave per bucket stripe
  int wid = t >> 6, lane = t & 63;
  for (int bk = wid; bk < NBUCK; bk += BPT / 64) {
    int lo = loff[bk];
    int hi = (bk + 1 < NBUCK) ? loff[bk + 1] : total;
    int gb = gbase[bk];
    for (int i = lo + lane; i < hi; i += 64) packed[gb + (i - lo)] = stage[i];
  }
}

__global__ __launch_bounds__(256) void k_bucket(const int* __restrict__ packed,
                                                const int* __restrict__ bucket_base,
                                                int* __restrict__ row_start,
                                                float* __restrict__ dinv,
                                                int* __restrict__ col, int E) {
  __shared__ int stage[CAP];
  __shared__ int hist[256];
  __shared__ int off[256];
  __shared__ int cur[256];
  int b = blockIdx.x, t = threadIdx.x;
  int base = bucket_base[b];
  int cnt = bucket_base[b + 1] - base;
  hist[t] = 0;
  bool staged = (cnt <= CAP);
  if (staged)
    for (int i = t; i < cnt; i += 256) stage[i] = __builtin_nontemporal_load(packed + base + i);
  __syncthreads();
  if (staged) {
    for (int i = t; i < cnt; i += 256) atomicAdd(&hist[stage[i] & 255], 1);
  } else {
    for (int i = t; i < cnt; i += 256) atomicAdd(&hist[packed[base + i] & 255], 1);
  }
  __syncthreads();
  int v = hist[t];
  off[t] = v;
  __syncthreads();
  for (int o = 1; o < 256; o <<= 1) {
    int add = (t >= o) ? off[t - o] : 0;
    __syncthreads();
    off[t] += add;
    __syncthreads();
  }
  int excl = off[t] - v;
  cur[t] = excl;
  int d = b * 256 + t;
  if (d < NN) {
    row_start[d] = base + excl;
    dinv[d] = rsqrtf((float)(v + 1));  // +1 self-loop
  }
  if (b == 0 && t == 0) row_start[NN] = E;
  __syncthreads();
  if (staged) {
    for (int i = t; i < cnt; i += 256) {
      int p = stage[i];
      int pos = atomicAdd(&cur[p & 255], 1);
      col[base + pos] = p >> 8;
    }
  } else {
    for (int i = t; i < cnt; i += 256) {
      int p = packed[base + i];
      int pos = atomicAdd(&cur[p & 255], 1);
      col[base + pos] = p >> 8;
    }
  }
}

// ==================== tab1 = fp16(dinv * (x @ W1)), [N][16] fp16 (3.2 MB) ====================
__global__ __launch_bounds__(256) void k_lin1(const float* __restrict__ x,
                                              const float* __restrict__ W1,
                                              const float* __restrict__ dinv,
                                              unsigned* __restrict__ tab1) {
  __shared__ float4 wl[F0 * 4];  // [k][jq], 8 KB
  int t = threadIdx.x;
  for (int i = t; i < F0 * 4; i += 256) wl[i] = ((const float4*)W1)[i];
  __syncthreads();
  int row0 = (blockIdx.x * 256 + t) * 4;
  if (row0 >= NN) return;  // N % 4 == 0
  float4 acc[4][4];
#pragma unroll
  for (int r = 0; r < 4; r++)
#pragma unroll
    for (int j = 0; j < 4; j++) acc[r][j] = make_float4(0.f, 0.f, 0.f, 0.f);
  const float4* xr0 = (const float4*)(x + (size_t)(row0 + 0) * F0);
  const float4* xr1 = (const float4*)(x + (size_t)(row0 + 1) * F0);
  const float4* xr2 = (const float4*)(x + (size_t)(row0 + 2) * F0);
  const float4* xr3 = (const float4*)(x + (size_t)(row0 + 3) * F0);
  for (int k4 = 0; k4 < F0 / 4; k4++) {
    float4 xv[4];
    xv[0] = xr0[k4]; xv[1] = xr1[k4]; xv[2] = xr2[k4]; xv[3] = xr3[k4];
#pragma unroll
    for (int kk = 0; kk < 4; kk++) {
      float4 w0 = wl[(k4 * 4 + kk) * 4 + 0];
      float4 w1 = wl[(k4 * 4 + kk) * 4 + 1];
      float4 w2 = wl[(k4 * 4 + kk) * 4 + 2];
      float4 w3 = wl[(k4 * 4 + kk) * 4 + 3];
#pragma unroll
      for (int r = 0; r < 4; r++) {
        float xs = kk == 0 ? xv[r].x : kk == 1 ? xv[r].y : kk == 2 ? xv[r].z : xv[r].w;
        fma4(acc[r][0], xs, w0);
        fma4(acc[r][1], xs, w1);
        fma4(acc[r][2], xs, w2);
        fma4(acc[r][3], xs, w3);
      }
    }
  }
#pragma unroll
  for (int r = 0; r < 4; r++) {
    float dd = dinv[row0 + r];
    float4 a0 = acc[r][0], a1 = acc[r][1], a2 = acc[r][2], a3 = acc[r][3];
    uint4 o0, o1;
    o0.x = pk2(dd * a0.x, dd * a0.y);
    o0.y = pk2(dd * a0.z, dd * a0.w);
    o0.z = pk2(dd * a1.x, dd * a1.y);
    o0.w = pk2(dd * a1.z, dd * a1.w);
    o1.x = pk2(dd * a2.x, dd * a2.y);
    o1.y = pk2(dd * a2.z, dd * a2.w);
    o1.z = pk2(dd * a3.x, dd * a3.y);
    o1.w = pk2(dd * a3.z, dd * a3.w);
    uint4* orow = (uint4*)(tab1 + (size_t)(row0 + r) * 8);
    orow[0] = o0;
    orow[1] = o1;
  }
}

// ==================== agg1 (+bias+ReLU) fused with lin2; 2 threads/dst ====================
__global__ __launch_bounds__(256) void k_agg1(const uint4* __restrict__ tab1,
                                              const int* __restrict__ row_start,
                                              const int* __restrict__ col,
                                              const float* __restrict__ dinv,
                                              const float* __restrict__ b1,
                                              const float* __restrict__ W2g,
                                              unsigned* __restrict__ tab2) {
  __shared__ float w2[F1][F2];
  __shared__ float b1l[F1];
  int t = threadIdx.x;
  if (t < F1 * F2) w2[t / F2][t % F2] = W2g[t];
  if (t < F1) b1l[t] = b1[t];
  __syncthreads();
  int g = blockIdx.x * 256 + t;
  int d = g >> 1, q = g & 1;
  if (d >= NN) return;
  float a[8] = {0, 0, 0, 0, 0, 0, 0, 0};
  auto addv = [&](uint4 v) {
    float2 f0 = up2(v.x), f1 = up2(v.y), f2 = up2(v.z), f3 = up2(v.w);
    a[0] += f0.x; a[1] += f0.y; a[2] += f1.x; a[3] += f1.y;
    a[4] += f2.x; a[5] += f2.y; a[6] += f3.x; a[7] += f3.y;
  };
  addv(tab1[2 * d + q]);  // self-loop row
  int e = row_start[d], e1 = row_start[d + 1];
  for (; e + 1 < e1; e += 2) {
    int s0 = __builtin_nontemporal_load(col + e);
    int s1 = __builtin_nontemporal_load(col + e + 1);
    uint4 v0 = tab1[2 * s0 + q];
    uint4 v1 = tab1[2 * s1 + q];
    addv(v0);
    addv(v1);
  }
  if (e < e1) addv(tab1[2 * __builtin_nontemporal_load(col + e) + q]);
  float dd = dinv[d];
  float h[8];
#pragma unroll
  for (int j = 0; j < 8; j++) h[j] = fmaxf(fmaf(dd, a[j], b1l[q * 8 + j]), 0.f);
  float p[F2];
#pragma unroll
  for (int j = 0; j < F2; j++) {
    float s = 0.f;
#pragma unroll
    for (int kk = 0; kk < 8; kk++) s = fmaf(h[kk], w2[q * 8 + kk][j], s);
    p[j] = s;
  }
#pragma unroll
  for (int j = 0; j < F2; j++) p[j] += __shfl_xor(p[j], 1);
  if (q == 0) {
    uint4 o;
    o.x = pk2(dd * p[0], dd * p[1]);
    o.y = pk2(dd * p[2], dd * p[3]);
    o.z = pk2(dd * p[4], dd * p[5]);
    o.w = pk2(dd * p[6], dd * p[7]);
    *(uint4*)(tab2 + (size_t)d * 8) = o;
  } else {
    tab2[(size_t)d * 8 + 4] = pk2(dd * p[8], dd * p[9]);
  }
}

// ==================== agg2 + bias + log_softmax; 1 thread/dst ====================
__global__ __launch_bounds__(256) void k_agg2(const unsigned* __restrict__ tab2,
                                              const int* __restrict__ row_start,
                                              const int* __restrict__ col,
                                              const float* __restrict__ dinv,
                                              const float* __restrict__ b2,
                                              float* __restrict__ out) {
  __shared__ float b2l[F2];
  int t = threadIdx.x;
  if (t < F2) b2l[t] = b2[t];
  __syncthreads();
  int d = blockIdx.x * 256 + t;
  if (d >= NN) return;
  float a[10] = {0, 0, 0, 0, 0, 0, 0, 0, 0, 0};
  auto addv = [&](int s) {
    const uint4 v = *(const uint4*)(tab2 + (size_t)s * 8);
    unsigned w = tab2[(size_t)s * 8 + 4];
    float2 f0 = up2(v.x), f1 = up2(v.y), f2 = up2(v.z), f3 = up2(v.w), f4 = up2(w);
    a[0] += f0.x; a[1] += f0.y; a[2] += f1.x; a[3] += f1.y;
    a[4] += f2.x; a[5] += f2.y; a[6] += f3.x; a[7] += f3.y;
    a[8] += f4.x; a[9] += f4.y;
  };
  addv(d);  // self-loop
  int e = row_start[d], e1 = row_start[d + 1];
  for (; e + 1 < e1; e += 2) {
    int s0 = __builtin_nontemporal_load(col + e);
    int s1 = __builtin_nontemporal_load(col + e + 1);
    addv(s0);
    addv(s1);
  }
  if (e < e1) addv(__builtin_nontemporal_load(col + e));
  float dd = dinv[d];
  float v[10];
#pragma unroll
  for (int j = 0; j < F2; j++) v[j] = fmaf(dd, a[j], b2l[j]);
  float m = v[0];
#pragma unroll
  for (int j = 1; j < F2; j++) m = fmaxf(m, v[j]);
  float sum = 0.f;
#pragma unroll
  for (int j = 0; j < F2; j++) sum += expf(v[j] - m);
  float lse = m + logf(sum);
  float2* o = (float2*)(out + (size_t)d * F2);
#pragma unroll
  for (int j = 0; j < 5; j++) o[j] = make_float2(v[2 * j] - lse, v[2 * j + 1] - lse);
}

extern "C" void kernel_launch(void* const* d_in, const int* in_sizes, int n_in,
                              void* d_out, int out_size, void* d_ws, size_t ws_size,
                              hipStream_t stream) {
  const float* x  = (const float*)d_in[0];
  const int*   ei = (const int*)d_in[1];
  const float* W1 = (const float*)d_in[2];
  const float* b1 = (const float*)d_in[3];
  const float* W2 = (const float*)d_in[4];
  const float* b2 = (const float*)d_in[5];
  float* out = (float*)d_out;
  int E = in_sizes[1] / 2;
  const int* src = ei;
  const int* dst = ei + E;

  char* p = (char*)d_ws;
  auto alloc = [&](size_t bytes) {
    char* r = p;
    p += (bytes + 255) & ~(size_t)255;
    return r;
  };
  size_t tabsz = (size_t)NN * 8 * 4;  // 3.2 MB ([N][16] fp16 = [N][8] uints)
  float* dinv        = (float*)alloc((size_t)NN * 4);
  int*   row_start   = (int*)alloc((size_t)(NN + 1) * 4);
  int*   bucket_cnt  = (int*)alloc((size_t)NBUCK * 4);
  int*   bucket_base = (int*)alloc((size_t)(NBUCK + 1) * 4);
  int*   bucket_cur  = (int*)alloc((size_t)NBUCK * 4);
  int*   col         = (int*)alloc((size_t)E * 4);
  // regionA: packed (E ints, 12.8 MB) dead after k_bucket; tab1+tab2 (6.4 MB) overlay it.
  size_t needA = tabsz * 2;
  size_t regA = (size_t)E * 4;
  char*  A = (char*)alloc(regA > needA ? regA : needA);
  int*      packed = (int*)A;
  unsigned* tab1 = (unsigned*)A;
  unsigned* tab2 = (unsigned*)(A + tabsz);

  int nblkN  = (NN + 255) / 256;        // 391
  int nblk2N = (2 * NN + 255) / 256;    // 782
  int nblk_place = (E + TILE - 1) / TILE;
  hipLaunchKernelGGL(k_zero, dim3(2), dim3(256), 0, stream, bucket_cnt);
  hipLaunchKernelGGL(k_bincount, dim3(256), dim3(256), 0, stream, dst, E, bucket_cnt);
  hipLaunchKernelGGL(k_binscan, dim3(1), dim3(512), 0, stream, bucket_cnt, bucket_base, bucket_cur);
  hipLaunchKernelGGL(k_binplace, dim3(nblk_place), dim3(BPT), 0, stream, src, dst, E, bucket_cur, packed);
  hipLaunchKernelGGL(k_bucket, dim3(NBUCK), dim3(256), 0, stream, packed, bucket_base, row_start, dinv, col, E);
  hipLaunchKernelGGL(k_lin1, dim3((NN / 4 + 255) / 256), dim3(256), 0, stream, x, W1, dinv, tab1);
  hipLaunchKernelGGL(k_agg1, dim3(nblk2N), dim3(256), 0, stream,
                     (const uint4*)tab1, row_start, col, dinv, b1, W2, tab2);
  hipLaunchKernelGGL(k_agg2, dim3(nblkN), dim3(256), 0, stream, tab2, row_start, col, dinv, b2, out);
}

// Round 7
// 214.274 us; speedup vs baseline: 2.1480x; 1.1395x over previous
//
#include <hip/hip_runtime.h>
#include <hip/hip_fp16.h>
#include <math.h>

#define NN 100000
#define F0 128
#define F1 16
#define F2 10
#define NBUCK 391   // ceil(NN / 256)
#define TILE 16384  // edges per binplace block
#define CAP 16384   // LDS staging capacity in k_bucket
#define BPT 512     // binplace threads

__device__ inline void fma4(float4& a, float s, const float4& w) {
  a.x = fmaf(s, w.x, a.x);
  a.y = fmaf(s, w.y, a.y);
  a.z = fmaf(s, w.z, a.z);
  a.w = fmaf(s, w.w, a.w);
}

__device__ inline unsigned pk2(float a, float b) {
  __half ha = __float2half(a), hb = __float2half(b);
  return (unsigned)__half_as_ushort(ha) | ((unsigned)__half_as_ushort(hb) << 16);
}

__device__ inline float2 up2(unsigned u) {
  __half2 h;
  *(unsigned*)&h = u;
  return __half22float2(h);
}

__device__ inline void nt_store_f2(float a, float b, float* p) {
  // pack two floats into a double and nt-store 8B (float2* is rejected by the builtin)
  union { double d; float f[2]; } u;
  u.f[0] = a; u.f[1] = b;
  __builtin_nontemporal_store(u.d, (double*)p);
}

// ==================== CSR build (two-level counting sort) ====================
__global__ void k_zero(int* __restrict__ bucket_cnt) {
  int i = blockIdx.x * blockDim.x + threadIdx.x;
  if (i < NBUCK) bucket_cnt[i] = 0;
}

__global__ __launch_bounds__(256) void k_bincount(const int* __restrict__ dst, int E,
                                                  int* __restrict__ bucket_cnt) {
  __shared__ int hist[NBUCK];
  int t = threadIdx.x;
  for (int i = t; i < NBUCK; i += 256) hist[i] = 0;
  __syncthreads();
  int per = (E + gridDim.x - 1) / gridDim.x;
  int e0 = blockIdx.x * per, e1 = min(E, e0 + per);
  for (int e = e0 + t; e < e1; e += 256)
    atomicAdd(&hist[__builtin_nontemporal_load(dst + e) >> 8], 1);
  __syncthreads();
  for (int i = t; i < NBUCK; i += 256)
    if (hist[i]) atomicAdd(&bucket_cnt[i], hist[i]);
}

__global__ void k_binscan(const int* __restrict__ bucket_cnt, int* __restrict__ bucket_base,
                          int* __restrict__ bucket_cur) {
  __shared__ int lds[512];
  int t = threadIdx.x;
  int v = (t < NBUCK) ? bucket_cnt[t] : 0;
  lds[t] = v;
  __syncthreads();
  for (int o = 1; o < 512; o <<= 1) {
    int add = (t >= o) ? lds[t - o] : 0;
    __syncthreads();
    lds[t] += add;
    __syncthreads();
  }
  if (t < NBUCK) {
    int excl = lds[t] - v;
    bucket_base[t] = excl;
    bucket_cur[t] = excl;
    if (t == NBUCK - 1) bucket_base[NBUCK] = lds[t];  // == E
  }
}

// LDS-reorder binplace: tile -> LDS (sorted by bucket) -> contiguous run copies.
__global__ __launch_bounds__(BPT) void k_binplace(const int* __restrict__ src,
                                                  const int* __restrict__ dst, int E,
                                                  int* __restrict__ bucket_cur,
                                                  int* __restrict__ packed) {
  __shared__ int cnt[NBUCK];    // counts -> cursor
  __shared__ int loff[NBUCK];   // local exclusive offsets
  __shared__ int gbase[NBUCK];  // global base of this block's run per bucket
  __shared__ int part[256];     // scan partials
  __shared__ int stage[TILE];   // 64 KB reorder buffer
  int t = threadIdx.x;
  int e0 = blockIdx.x * TILE, e1 = min(E, e0 + TILE);
  int total = e1 - e0;
  for (int i = t; i < NBUCK; i += BPT) cnt[i] = 0;
  __syncthreads();
  for (int e = e0 + t; e < e1; e += BPT)
    atomicAdd(&cnt[__builtin_nontemporal_load(dst + e) >> 8], 1);
  __syncthreads();
  // reserve global space per bucket
  for (int i = t; i < NBUCK; i += BPT) {
    int c = cnt[i];
    gbase[i] = c ? atomicAdd(&bucket_cur[i], c) : 0;
  }
  // block scan of cnt -> loff (256 owners x 2 entries)
  if (t < 256) {
    int i0 = 2 * t, i1 = 2 * t + 1;
    int c0 = (i0 < NBUCK) ? cnt[i0] : 0;
    int c1 = (i1 < NBUCK) ? cnt[i1] : 0;
    part[t] = c0 + c1;
  }
  __syncthreads();
  for (int o = 1; o < 256; o <<= 1) {
    int add = 0;
    if (t < 256 && t >= o) add = part[t - o];
    __syncthreads();
    if (t < 256) part[t] += add;
    __syncthreads();
  }
  if (t < 256) {
    int i0 = 2 * t, i1 = 2 * t + 1;
    int c0 = (i0 < NBUCK) ? cnt[i0] : 0;
    int c1 = (i1 < NBUCK) ? cnt[i1] : 0;
    int excl = part[t] - c0 - c1;
    if (i0 < NBUCK) loff[i0] = excl;
    if (i1 < NBUCK) loff[i1] = excl + c0;
  }
  __syncthreads();
  for (int i = t; i < NBUCK; i += BPT) cnt[i] = loff[i];  // cursor
  __syncthreads();
  // scatter tile into LDS, sorted by bucket
  for (int e = e0 + t; e < e1; e += BPT) {
    int d = __builtin_nontemporal_load(dst + e);
    int s = __builtin_nontemporal_load(src + e);
    int bk = d >> 8;
    int pos = atomicAdd(&cnt[bk], 1);
    stage[pos] = (s << 8) | (d & 255);
  }
  __syncthreads();
  // contiguous run copy: one wave per bucket stripe
  int wid = t >> 6, lane = t & 63;
  for (int bk = wid; bk < NBUCK; bk += BPT / 64) {
    int lo = loff[bk];
    int hi = (bk + 1 < NBUCK) ? loff[bk + 1] : total;
    int gb = gbase[bk];
    for (int i = lo + lane; i < hi; i += 64) packed[gb + (i - lo)] = stage[i];
  }
}

__global__ __launch_bounds__(256) void k_bucket(const int* __restrict__ packed,
                                                const int* __restrict__ bucket_base,
                                                int* __restrict__ row_start,
                                                float* __restrict__ dinv,
                                                int* __restrict__ col, int E) {
  __shared__ int stage[CAP];
  __shared__ int hist[256];
  __shared__ int off[256];
  __shared__ int cur[256];
  int b = blockIdx.x, t = threadIdx.x;
  int base = bucket_base[b];
  int cnt = bucket_base[b + 1] - base;
  hist[t] = 0;
  bool staged = (cnt <= CAP);
  if (staged)
    for (int i = t; i < cnt; i += 256) stage[i] = __builtin_nontemporal_load(packed + base + i);
  __syncthreads();
  if (staged) {
    for (int i = t; i < cnt; i += 256) atomicAdd(&hist[stage[i] & 255], 1);
  } else {
    for (int i = t; i < cnt; i += 256) atomicAdd(&hist[packed[base + i] & 255], 1);
  }
  __syncthreads();
  int v = hist[t];
  off[t] = v;
  __syncthreads();
  for (int o = 1; o < 256; o <<= 1) {
    int add = (t >= o) ? off[t - o] : 0;
    __syncthreads();
    off[t] += add;
    __syncthreads();
  }
  int excl = off[t] - v;
  cur[t] = excl;
  int d = b * 256 + t;
  if (d < NN) {
    row_start[d] = base + excl;
    dinv[d] = rsqrtf((float)(v + 1));  // +1 self-loop
  }
  if (b == 0 && t == 0) row_start[NN] = E;
  __syncthreads();
  if (staged) {
    for (int i = t; i < cnt; i += 256) {
      int p = stage[i];
      int pos = atomicAdd(&cur[p & 255], 1);
      col[base + pos] = p >> 8;
    }
  } else {
    for (int i = t; i < cnt; i += 256) {
      int p = packed[base + i];
      int pos = atomicAdd(&cur[p & 255], 1);
      col[base + pos] = p >> 8;
    }
  }
}

// ==================== tab1 = fp16(dinv * (x @ W1)), [N][16] fp16 (3.2 MB) ====================
__global__ __launch_bounds__(256) void k_lin1(const float* __restrict__ x,
                                              const float* __restrict__ W1,
                                              const float* __restrict__ dinv,
                                              unsigned* __restrict__ tab1) {
  __shared__ float4 wl[F0 * 4];  // [k][jq], 8 KB
  int t = threadIdx.x;
  for (int i = t; i < F0 * 4; i += 256) wl[i] = ((const float4*)W1)[i];
  __syncthreads();
  int row0 = (blockIdx.x * 256 + t) * 4;
  if (row0 >= NN) return;  // N % 4 == 0
  float4 acc[4][4];
#pragma unroll
  for (int r = 0; r < 4; r++)
#pragma unroll
    for (int j = 0; j < 4; j++) acc[r][j] = make_float4(0.f, 0.f, 0.f, 0.f);
  const float4* xr0 = (const float4*)(x + (size_t)(row0 + 0) * F0);
  const float4* xr1 = (const float4*)(x + (size_t)(row0 + 1) * F0);
  const float4* xr2 = (const float4*)(x + (size_t)(row0 + 2) * F0);
  const float4* xr3 = (const float4*)(x + (size_t)(row0 + 3) * F0);
  for (int k4 = 0; k4 < F0 / 4; k4++) {
    float4 xv[4];
    xv[0] = xr0[k4]; xv[1] = xr1[k4]; xv[2] = xr2[k4]; xv[3] = xr3[k4];
#pragma unroll
    for (int kk = 0; kk < 4; kk++) {
      float4 w0 = wl[(k4 * 4 + kk) * 4 + 0];
      float4 w1 = wl[(k4 * 4 + kk) * 4 + 1];
      float4 w2 = wl[(k4 * 4 + kk) * 4 + 2];
      float4 w3 = wl[(k4 * 4 + kk) * 4 + 3];
#pragma unroll
      for (int r = 0; r < 4; r++) {
        float xs = kk == 0 ? xv[r].x : kk == 1 ? xv[r].y : kk == 2 ? xv[r].z : xv[r].w;
        fma4(acc[r][0], xs, w0);
        fma4(acc[r][1], xs, w1);
        fma4(acc[r][2], xs, w2);
        fma4(acc[r][3], xs, w3);
      }
    }
  }
#pragma unroll
  for (int r = 0; r < 4; r++) {
    float dd = dinv[row0 + r];
    float4 a0 = acc[r][0], a1 = acc[r][1], a2 = acc[r][2], a3 = acc[r][3];
    uint4 o0, o1;
    o0.x = pk2(dd * a0.x, dd * a0.y);
    o0.y = pk2(dd * a0.z, dd * a0.w);
    o0.z = pk2(dd * a1.x, dd * a1.y);
    o0.w = pk2(dd * a1.z, dd * a1.w);
    o1.x = pk2(dd * a2.x, dd * a2.y);
    o1.y = pk2(dd * a2.z, dd * a2.w);
    o1.z = pk2(dd * a3.x, dd * a3.y);
    o1.w = pk2(dd * a3.z, dd * a3.w);
    uint4* orow = (uint4*)(tab1 + (size_t)(row0 + r) * 8);
    orow[0] = o0;
    orow[1] = o1;
  }
}

// ==================== agg1 (+bias+ReLU) fused with lin2; 4-thread quad per dst ====================
// Each quad thread accumulates ALL 16 features over 1/4 of the edges; shfl_xor quad reduce.
__global__ __launch_bounds__(256) void k_agg1(const uint4* __restrict__ tab1,
                                              const int* __restrict__ row_start,
                                              const int* __restrict__ col,
                                              const float* __restrict__ dinv,
                                              const float* __restrict__ b1,
                                              const float* __restrict__ W2g,
                                              unsigned* __restrict__ tab2) {
  __shared__ float w2[F1][F2];
  __shared__ float b1l[F1];
  int t = threadIdx.x;
  if (t < F1 * F2) w2[t / F2][t % F2] = W2g[t];
  if (t < F1) b1l[t] = b1[t];
  __syncthreads();
  int g = blockIdx.x * 256 + t;
  int d = g >> 2, q = g & 3;
  if (d >= NN) return;
  float a[16];
#pragma unroll
  for (int j = 0; j < 16; j++) a[j] = 0.f;
  auto addrow = [&](int s) {
    uint4 v0 = tab1[2 * s];
    uint4 v1 = tab1[2 * s + 1];
    float2 f;
    f = up2(v0.x); a[0] += f.x; a[1] += f.y;
    f = up2(v0.y); a[2] += f.x; a[3] += f.y;
    f = up2(v0.z); a[4] += f.x; a[5] += f.y;
    f = up2(v0.w); a[6] += f.x; a[7] += f.y;
    f = up2(v1.x); a[8] += f.x; a[9] += f.y;
    f = up2(v1.y); a[10] += f.x; a[11] += f.y;
    f = up2(v1.z); a[12] += f.x; a[13] += f.y;
    f = up2(v1.w); a[14] += f.x; a[15] += f.y;
  };
  if (q == 0) addrow(d);  // self-loop row
  int e = row_start[d] + q, e1 = row_start[d + 1];
  for (; e + 4 < e1; e += 8) {
    int s0 = __builtin_nontemporal_load(col + e);
    int s1 = __builtin_nontemporal_load(col + e + 4);
    addrow(s0);
    addrow(s1);
  }
  if (e < e1) addrow(__builtin_nontemporal_load(col + e));
#pragma unroll
  for (int j = 0; j < 16; j++) a[j] += __shfl_xor(a[j], 1);
#pragma unroll
  for (int j = 0; j < 16; j++) a[j] += __shfl_xor(a[j], 2);
  if (q >= 2) return;
  float dd = dinv[d];
  float h[16];
#pragma unroll
  for (int j = 0; j < 16; j++) h[j] = fmaxf(fmaf(dd, a[j], b1l[j]), 0.f);
  if (q == 0) {
    float p[8];
#pragma unroll
    for (int j = 0; j < 8; j++) {
      float s = 0.f;
#pragma unroll
      for (int kk = 0; kk < 16; kk++) s = fmaf(h[kk], w2[kk][j], s);
      p[j] = s;
    }
    uint4 o;
    o.x = pk2(dd * p[0], dd * p[1]);
    o.y = pk2(dd * p[2], dd * p[3]);
    o.z = pk2(dd * p[4], dd * p[5]);
    o.w = pk2(dd * p[6], dd * p[7]);
    *(uint4*)(tab2 + (size_t)d * 8) = o;
  } else {
    float p8 = 0.f, p9 = 0.f;
#pragma unroll
    for (int kk = 0; kk < 16; kk++) {
      p8 = fmaf(h[kk], w2[kk][8], p8);
      p9 = fmaf(h[kk], w2[kk][9], p9);
    }
    tab2[(size_t)d * 8 + 4] = pk2(dd * p8, dd * p9);
  }
}

// ==================== agg2 + bias + log_softmax; 4-thread quad per dst ====================
__global__ __launch_bounds__(256) void k_agg2(const unsigned* __restrict__ tab2,
                                              const int* __restrict__ row_start,
                                              const int* __restrict__ col,
                                              const float* __restrict__ dinv,
                                              const float* __restrict__ b2,
                                              float* __restrict__ out) {
  __shared__ float b2l[F2];
  int t = threadIdx.x;
  if (t < F2) b2l[t] = b2[t];
  __syncthreads();
  int g = blockIdx.x * 256 + t;
  int d = g >> 2, q = g & 3;
  if (d >= NN) return;
  float a[10];
#pragma unroll
  for (int j = 0; j < 10; j++) a[j] = 0.f;
  auto addrow = [&](int s) {
    uint4 v = *(const uint4*)(tab2 + (size_t)s * 8);
    unsigned w = tab2[(size_t)s * 8 + 4];
    float2 f;
    f = up2(v.x); a[0] += f.x; a[1] += f.y;
    f = up2(v.y); a[2] += f.x; a[3] += f.y;
    f = up2(v.z); a[4] += f.x; a[5] += f.y;
    f = up2(v.w); a[6] += f.x; a[7] += f.y;
    f = up2(w);   a[8] += f.x; a[9] += f.y;
  };
  if (q == 0) addrow(d);  // self-loop
  int e = row_start[d] + q, e1 = row_start[d + 1];
  for (; e + 4 < e1; e += 8) {
    int s0 = __builtin_nontemporal_load(col + e);
    int s1 = __builtin_nontemporal_load(col + e + 4);
    addrow(s0);
    addrow(s1);
  }
  if (e < e1) addrow(__builtin_nontemporal_load(col + e));
#pragma unroll
  for (int j = 0; j < 10; j++) a[j] += __shfl_xor(a[j], 1);
#pragma unroll
  for (int j = 0; j < 10; j++) a[j] += __shfl_xor(a[j], 2);
  if (q >= 3) return;
  float dd = dinv[d];
  float v[10];
#pragma unroll
  for (int j = 0; j < F2; j++) v[j] = fmaf(dd, a[j], b2l[j]);
  float m = v[0];
#pragma unroll
  for (int j = 1; j < F2; j++) m = fmaxf(m, v[j]);
  float sum = 0.f;
#pragma unroll
  for (int j = 0; j < F2; j++) sum += expf(v[j] - m);
  float lse = m + logf(sum);
  float* o = out + (size_t)d * F2;  // rows are 40 B -> 8 B aligned
  if (q == 0) {
    nt_store_f2(v[0] - lse, v[1] - lse, o + 0);
    nt_store_f2(v[2] - lse, v[3] - lse, o + 2);
  } else if (q == 1) {
    nt_store_f2(v[4] - lse, v[5] - lse, o + 4);
    nt_store_f2(v[6] - lse, v[7] - lse, o + 6);
  } else {
    nt_store_f2(v[8] - lse, v[9] - lse, o + 8);
  }
}

extern "C" void kernel_launch(void* const* d_in, const int* in_sizes, int n_in,
                              void* d_out, int out_size, void* d_ws, size_t ws_size,
                              hipStream_t stream) {
  const float* x  = (const float*)d_in[0];
  const int*   ei = (const int*)d_in[1];
  const float* W1 = (const float*)d_in[2];
  const float* b1 = (const float*)d_in[3];
  const float* W2 = (const float*)d_in[4];
  const float* b2 = (const float*)d_in[5];
  float* out = (float*)d_out;
  int E = in_sizes[1] / 2;
  const int* src = ei;
  const int* dst = ei + E;

  char* p = (char*)d_ws;
  auto alloc = [&](size_t bytes) {
    char* r = p;
    p += (bytes + 255) & ~(size_t)255;
    return r;
  };
  size_t tabsz = (size_t)NN * 8 * 4;  // 3.2 MB ([N][16] fp16 = [N][8] uints)
  float* dinv        = (float*)alloc((size_t)NN * 4);
  int*   row_start   = (int*)alloc((size_t)(NN + 1) * 4);
  int*   bucket_cnt  = (int*)alloc((size_t)NBUCK * 4);
  int*   bucket_base = (int*)alloc((size_t)(NBUCK + 1) * 4);
  int*   bucket_cur  = (int*)alloc((size_t)NBUCK * 4);
  int*   col         = (int*)alloc((size_t)E * 4);
  // regionA: packed (E ints, 12.8 MB) dead after k_bucket; tab1+tab2 (6.4 MB) overlay it.
  size_t needA = tabsz * 2;
  size_t regA = (size_t)E * 4;
  char*  A = (char*)alloc(regA > needA ? regA : needA);
  int*      packed = (int*)A;
  unsigned* tab1 = (unsigned*)A;
  unsigned* tab2 = (unsigned*)(A + tabsz);

  int nblk4N = (4 * NN + 255) / 256;    // 1563
  int nblk_place = (E + TILE - 1) / TILE;
  hipLaunchKernelGGL(k_zero, dim3(2), dim3(256), 0, stream, bucket_cnt);
  hipLaunchKernelGGL(k_bincount, dim3(256), dim3(256), 0, stream, dst, E, bucket_cnt);
  hipLaunchKernelGGL(k_binscan, dim3(1), dim3(512), 0, stream, bucket_cnt, bucket_base, bucket_cur);
  hipLaunchKernelGGL(k_binplace, dim3(nblk_place), dim3(BPT), 0, stream, src, dst, E, bucket_cur, packed);
  hipLaunchKernelGGL(k_bucket, dim3(NBUCK), dim3(256), 0, stream, packed, bucket_base, row_start, dinv, col, E);
  hipLaunchKernelGGL(k_lin1, dim3((NN / 4 + 255) / 256), dim3(256), 0, stream, x, W1, dinv, tab1);
  hipLaunchKernelGGL(k_agg1, dim3(nblk4N), dim3(256), 0, stream,
                     (const uint4*)tab1, row_start, col, dinv, b1, W2, tab2);
  hipLaunchKernelGGL(k_agg2, dim3(nblk4N), dim3(256), 0, stream, tab2, row_start, col, dinv, b2, out);
}

// Round 8
// 214.147 us; speedup vs baseline: 2.1493x; 1.0006x over previous
//
#include <hip/hip_runtime.h>
#include <hip/hip_fp16.h>
#include <math.h>

#define NN 100000
#define F0 128
#define F1 16
#define F2 10
#define NBUCK 391   // ceil(NN / 256)
#define TILE 4096   // edges per binplace block (16KB stage -> ~3 blocks/CU)
#define CAP 16384   // LDS staging capacity in k_bucket
#define BPT 512     // binplace threads

__device__ inline void fma4(float4& a, float s, const float4& w) {
  a.x = fmaf(s, w.x, a.x);
  a.y = fmaf(s, w.y, a.y);
  a.z = fmaf(s, w.z, a.z);
  a.w = fmaf(s, w.w, a.w);
}

__device__ inline unsigned pk2(float a, float b) {
  __half ha = __float2half(a), hb = __float2half(b);
  return (unsigned)__half_as_ushort(ha) | ((unsigned)__half_as_ushort(hb) << 16);
}

__device__ inline float2 up2(unsigned u) {
  __half2 h;
  *(unsigned*)&h = u;
  return __half22float2(h);
}

__device__ inline void nt_store_f2(float a, float b, float* p) {
  union { double d; float f[2]; } u;
  u.f[0] = a; u.f[1] = b;
  __builtin_nontemporal_store(u.d, (double*)p);
}

// ==================== CSR build (two-level counting sort) ====================
__global__ void k_zero(int* __restrict__ bucket_cnt) {
  int i = blockIdx.x * blockDim.x + threadIdx.x;
  if (i < NBUCK) bucket_cnt[i] = 0;
}

__global__ __launch_bounds__(256) void k_bincount(const int* __restrict__ dst, int E,
                                                  int* __restrict__ bucket_cnt) {
  __shared__ int hist[NBUCK];
  int t = threadIdx.x;
  for (int i = t; i < NBUCK; i += 256) hist[i] = 0;
  __syncthreads();
  int per = (E + gridDim.x - 1) / gridDim.x;
  int e0 = blockIdx.x * per, e1 = min(E, e0 + per);
  for (int e = e0 + t; e < e1; e += 256)
    atomicAdd(&hist[__builtin_nontemporal_load(dst + e) >> 8], 1);
  __syncthreads();
  for (int i = t; i < NBUCK; i += 256)
    if (hist[i]) atomicAdd(&bucket_cnt[i], hist[i]);
}

__global__ void k_binscan(const int* __restrict__ bucket_cnt, int* __restrict__ bucket_base,
                          int* __restrict__ bucket_cur) {
  __shared__ int lds[512];
  int t = threadIdx.x;
  int v = (t < NBUCK) ? bucket_cnt[t] : 0;
  lds[t] = v;
  __syncthreads();
  for (int o = 1; o < 512; o <<= 1) {
    int add = (t >= o) ? lds[t - o] : 0;
    __syncthreads();
    lds[t] += add;
    __syncthreads();
  }
  if (t < NBUCK) {
    int excl = lds[t] - v;
    bucket_base[t] = excl;
    bucket_cur[t] = excl;
    if (t == NBUCK - 1) bucket_base[NBUCK] = lds[t];  // == E
  }
}

// LDS-reorder binplace: tile -> LDS (sorted by bucket) -> contiguous run copies.
__global__ __launch_bounds__(BPT) void k_binplace(const int* __restrict__ src,
                                                  const int* __restrict__ dst, int E,
                                                  int* __restrict__ bucket_cur,
                                                  int* __restrict__ packed) {
  __shared__ int cnt[NBUCK];    // counts -> cursor
  __shared__ int loff[NBUCK];   // local exclusive offsets
  __shared__ int gbase[NBUCK];  // global base of this block's run per bucket
  __shared__ int part[256];     // scan partials
  __shared__ int stage[TILE];   // 16 KB reorder buffer
  int t = threadIdx.x;
  int e0 = blockIdx.x * TILE, e1 = min(E, e0 + TILE);
  int total = e1 - e0;
  for (int i = t; i < NBUCK; i += BPT) cnt[i] = 0;
  __syncthreads();
  for (int e = e0 + t; e < e1; e += BPT)
    atomicAdd(&cnt[__builtin_nontemporal_load(dst + e) >> 8], 1);
  __syncthreads();
  // reserve global space per bucket
  for (int i = t; i < NBUCK; i += BPT) {
    int c = cnt[i];
    gbase[i] = c ? atomicAdd(&bucket_cur[i], c) : 0;
  }
  // block scan of cnt -> loff (256 owners x 2 entries)
  if (t < 256) {
    int i0 = 2 * t, i1 = 2 * t + 1;
    int c0 = (i0 < NBUCK) ? cnt[i0] : 0;
    int c1 = (i1 < NBUCK) ? cnt[i1] : 0;
    part[t] = c0 + c1;
  }
  __syncthreads();
  for (int o = 1; o < 256; o <<= 1) {
    int add = 0;
    if (t < 256 && t >= o) add = part[t - o];
    __syncthreads();
    if (t < 256) part[t] += add;
    __syncthreads();
  }
  if (t < 256) {
    int i0 = 2 * t, i1 = 2 * t + 1;
    int c0 = (i0 < NBUCK) ? cnt[i0] : 0;
    int c1 = (i1 < NBUCK) ? cnt[i1] : 0;
    int excl = part[t] - c0 - c1;
    if (i0 < NBUCK) loff[i0] = excl;
    if (i1 < NBUCK) loff[i1] = excl + c0;
  }
  __syncthreads();
  for (int i = t; i < NBUCK; i += BPT) cnt[i] = loff[i];  // cursor
  __syncthreads();
  // scatter tile into LDS, sorted by bucket
  for (int e = e0 + t; e < e1; e += BPT) {
    int d = __builtin_nontemporal_load(dst + e);
    int s = __builtin_nontemporal_load(src + e);
    int bk = d >> 8;
    int pos = atomicAdd(&cnt[bk], 1);
    stage[pos] = (s << 8) | (d & 255);
  }
  __syncthreads();
  // contiguous run copy: one wave per bucket stripe
  int wid = t >> 6, lane = t & 63;
  for (int bk = wid; bk < NBUCK; bk += BPT / 64) {
    int lo = loff[bk];
    int hi = (bk + 1 < NBUCK) ? loff[bk + 1] : total;
    int gb = gbase[bk];
    for (int i = lo + lane; i < hi; i += 64) packed[gb + (i - lo)] = stage[i];
  }
}

__global__ __launch_bounds__(256) void k_bucket(const int* __restrict__ packed,
                                                const int* __restrict__ bucket_base,
                                                int* __restrict__ row_start,
                                                float* __restrict__ dinv,
                                                int* __restrict__ col, int E) {
  __shared__ int stage[CAP];
  __shared__ int hist[256];
  __shared__ int off[256];
  __shared__ int cur[256];
  int b = blockIdx.x, t = threadIdx.x;
  int base = bucket_base[b];
  int cnt = bucket_base[b + 1] - base;
  hist[t] = 0;
  bool staged = (cnt <= CAP);
  if (staged)
    for (int i = t; i < cnt; i += 256) stage[i] = __builtin_nontemporal_load(packed + base + i);
  __syncthreads();
  if (staged) {
    for (int i = t; i < cnt; i += 256) atomicAdd(&hist[stage[i] & 255], 1);
  } else {
    for (int i = t; i < cnt; i += 256) atomicAdd(&hist[packed[base + i] & 255], 1);
  }
  __syncthreads();
  int v = hist[t];
  off[t] = v;
  __syncthreads();
  for (int o = 1; o < 256; o <<= 1) {
    int add = (t >= o) ? off[t - o] : 0;
    __syncthreads();
    off[t] += add;
    __syncthreads();
  }
  int excl = off[t] - v;
  cur[t] = excl;
  int d = b * 256 + t;
  if (d < NN) {
    row_start[d] = base + excl;
    dinv[d] = rsqrtf((float)(v + 1));  // +1 self-loop
  }
  if (b == 0 && t == 0) row_start[NN] = E;
  __syncthreads();
  if (staged) {
    for (int i = t; i < cnt; i += 256) {
      int p = stage[i];
      int pos = atomicAdd(&cur[p & 255], 1);
      col[base + pos] = p >> 8;
    }
  } else {
    for (int i = t; i < cnt; i += 256) {
      int p = packed[base + i];
      int pos = atomicAdd(&cur[p & 255], 1);
      col[base + pos] = p >> 8;
    }
  }
}

// ==================== tab1 = fp16(dinv * (x @ W1)), [N][16] fp16 (3.2 MB) ====================
__global__ __launch_bounds__(256) void k_lin1(const float* __restrict__ x,
                                              const float* __restrict__ W1,
                                              const float* __restrict__ dinv,
                                              unsigned* __restrict__ tab1) {
  __shared__ float4 wl[F0 * 4];  // [k][jq], 8 KB
  int t = threadIdx.x;
  for (int i = t; i < F0 * 4; i += 256) wl[i] = ((const float4*)W1)[i];
  __syncthreads();
  int row0 = (blockIdx.x * 256 + t) * 4;
  if (row0 >= NN) return;  // N % 4 == 0
  float4 acc[4][4];
#pragma unroll
  for (int r = 0; r < 4; r++)
#pragma unroll
    for (int j = 0; j < 4; j++) acc[r][j] = make_float4(0.f, 0.f, 0.f, 0.f);
  const float4* xr0 = (const float4*)(x + (size_t)(row0 + 0) * F0);
  const float4* xr1 = (const float4*)(x + (size_t)(row0 + 1) * F0);
  const float4* xr2 = (const float4*)(x + (size_t)(row0 + 2) * F0);
  const float4* xr3 = (const float4*)(x + (size_t)(row0 + 3) * F0);
  for (int k4 = 0; k4 < F0 / 4; k4++) {
    float4 xv[4];
    xv[0] = xr0[k4]; xv[1] = xr1[k4]; xv[2] = xr2[k4]; xv[3] = xr3[k4];
#pragma unroll
    for (int kk = 0; kk < 4; kk++) {
      float4 w0 = wl[(k4 * 4 + kk) * 4 + 0];
      float4 w1 = wl[(k4 * 4 + kk) * 4 + 1];
      float4 w2 = wl[(k4 * 4 + kk) * 4 + 2];
      float4 w3 = wl[(k4 * 4 + kk) * 4 + 3];
#pragma unroll
      for (int r = 0; r < 4; r++) {
        float xs = kk == 0 ? xv[r].x : kk == 1 ? xv[r].y : kk == 2 ? xv[r].z : xv[r].w;
        fma4(acc[r][0], xs, w0);
        fma4(acc[r][1], xs, w1);
        fma4(acc[r][2], xs, w2);
        fma4(acc[r][3], xs, w3);
      }
    }
  }
#pragma unroll
  for (int r = 0; r < 4; r++) {
    float dd = dinv[row0 + r];
    float4 a0 = acc[r][0], a1 = acc[r][1], a2 = acc[r][2], a3 = acc[r][3];
    uint4 o0, o1;
    o0.x = pk2(dd * a0.x, dd * a0.y);
    o0.y = pk2(dd * a0.z, dd * a0.w);
    o0.z = pk2(dd * a1.x, dd * a1.y);
    o0.w = pk2(dd * a1.z, dd * a1.w);
    o1.x = pk2(dd * a2.x, dd * a2.y);
    o1.y = pk2(dd * a2.z, dd * a2.w);
    o1.z = pk2(dd * a3.x, dd * a3.y);
    o1.w = pk2(dd * a3.z, dd * a3.w);
    uint4* orow = (uint4*)(tab1 + (size_t)(row0 + r) * 8);
    orow[0] = o0;
    orow[1] = o1;
  }
}

// ==================== agg1 (+bias+ReLU) fused with lin2; 4-thread quad per dst ====================
__global__ __launch_bounds__(256) void k_agg1(const uint4* __restrict__ tab1,
                                              const int* __restrict__ row_start,
                                              const int* __restrict__ col,
                                              const float* __restrict__ dinv,
                                              const float* __restrict__ b1,
                                              const float* __restrict__ W2g,
                                              unsigned* __restrict__ tab2) {
  __shared__ float w2[F1][F2];
  __shared__ float b1l[F1];
  int t = threadIdx.x;
  if (t < F1 * F2) w2[t / F2][t % F2] = W2g[t];
  if (t < F1) b1l[t] = b1[t];
  __syncthreads();
  int g = blockIdx.x * 256 + t;
  int d = g >> 2, q = g & 3;
  if (d >= NN) return;
  float a[16];
#pragma unroll
  for (int j = 0; j < 16; j++) a[j] = 0.f;
  auto addrow = [&](int s) {
    uint4 v0 = tab1[2 * s];
    uint4 v1 = tab1[2 * s + 1];
    float2 f;
    f = up2(v0.x); a[0] += f.x; a[1] += f.y;
    f = up2(v0.y); a[2] += f.x; a[3] += f.y;
    f = up2(v0.z); a[4] += f.x; a[5] += f.y;
    f = up2(v0.w); a[6] += f.x; a[7] += f.y;
    f = up2(v1.x); a[8] += f.x; a[9] += f.y;
    f = up2(v1.y); a[10] += f.x; a[11] += f.y;
    f = up2(v1.z); a[12] += f.x; a[13] += f.y;
    f = up2(v1.w); a[14] += f.x; a[15] += f.y;
  };
  if (q == 0) addrow(d);  // self-loop row
  int e = row_start[d] + q, e1 = row_start[d + 1];
  for (; e + 4 < e1; e += 8) {
    int s0 = __builtin_nontemporal_load(col + e);
    int s1 = __builtin_nontemporal_load(col + e + 4);
    addrow(s0);
    addrow(s1);
  }
  if (e < e1) addrow(__builtin_nontemporal_load(col + e));
#pragma unroll
  for (int j = 0; j < 16; j++) a[j] += __shfl_xor(a[j], 1);
#pragma unroll
  for (int j = 0; j < 16; j++) a[j] += __shfl_xor(a[j], 2);
  if (q >= 2) return;
  float dd = dinv[d];
  float h[16];
#pragma unroll
  for (int j = 0; j < 16; j++) h[j] = fmaxf(fmaf(dd, a[j], b1l[j]), 0.f);
  if (q == 0) {
    float p[8];
#pragma unroll
    for (int j = 0; j < 8; j++) {
      float s = 0.f;
#pragma unroll
      for (int kk = 0; kk < 16; kk++) s = fmaf(h[kk], w2[kk][j], s);
      p[j] = s;
    }
    uint4 o;
    o.x = pk2(dd * p[0], dd * p[1]);
    o.y = pk2(dd * p[2], dd * p[3]);
    o.z = pk2(dd * p[4], dd * p[5]);
    o.w = pk2(dd * p[6], dd * p[7]);
    *(uint4*)(tab2 + (size_t)d * 8) = o;
  } else {
    float p8 = 0.f, p9 = 0.f;
#pragma unroll
    for (int kk = 0; kk < 16; kk++) {
      p8 = fmaf(h[kk], w2[kk][8], p8);
      p9 = fmaf(h[kk], w2[kk][9], p9);
    }
    tab2[(size_t)d * 8 + 4] = pk2(dd * p8, dd * p9);
  }
}

// ==================== agg2 + bias + log_softmax; 4-thread quad per dst ====================
__global__ __launch_bounds__(256) void k_agg2(const unsigned* __restrict__ tab2,
                                              const int* __restrict__ row_start,
                                              const int* __restrict__ col,
                                              const float* __restrict__ dinv,
                                              const float* __restrict__ b2,
                                              float* __restrict__ out) {
  __shared__ float b2l[F2];
  int t = threadIdx.x;
  if (t < F2) b2l[t] = b2[t];
  __syncthreads();
  int g = blockIdx.x * 256 + t;
  int d = g >> 2, q = g & 3;
  if (d >= NN) return;
  float a[10];
#pragma unroll
  for (int j = 0; j < 10; j++) a[j] = 0.f;
  auto addrow = [&](int s) {
    uint4 v = *(const uint4*)(tab2 + (size_t)s * 8);
    unsigned w = tab2[(size_t)s * 8 + 4];
    float2 f;
    f = up2(v.x); a[0] += f.x; a[1] += f.y;
    f = up2(v.y); a[2] += f.x; a[3] += f.y;
    f = up2(v.z); a[4] += f.x; a[5] += f.y;
    f = up2(v.w); a[6] += f.x; a[7] += f.y;
    f = up2(w);   a[8] += f.x; a[9] += f.y;
  };
  if (q == 0) addrow(d);  // self-loop
  int e = row_start[d] + q, e1 = row_start[d + 1];
  for (; e + 4 < e1; e += 8) {
    int s0 = __builtin_nontemporal_load(col + e);
    int s1 = __builtin_nontemporal_load(col + e + 4);
    addrow(s0);
    addrow(s1);
  }
  if (e < e1) addrow(__builtin_nontemporal_load(col + e));
#pragma unroll
  for (int j = 0; j < 10; j++) a[j] += __shfl_xor(a[j], 1);
#pragma unroll
  for (int j = 0; j < 10; j++) a[j] += __shfl_xor(a[j], 2);
  if (q >= 3) return;
  float dd = dinv[d];
  float v[10];
#pragma unroll
  for (int j = 0; j < F2; j++) v[j] = fmaf(dd, a[j], b2l[j]);
  float m = v[0];
#pragma unroll
  for (int j = 1; j < F2; j++) m = fmaxf(m, v[j]);
  float sum = 0.f;
#pragma unroll
  for (int j = 0; j < F2; j++) sum += expf(v[j] - m);
  float lse = m + logf(sum);
  float* o = out + (size_t)d * F2;  // rows are 40 B -> 8 B aligned
  if (q == 0) {
    nt_store_f2(v[0] - lse, v[1] - lse, o + 0);
    nt_store_f2(v[2] - lse, v[3] - lse, o + 2);
  } else if (q == 1) {
    nt_store_f2(v[4] - lse, v[5] - lse, o + 4);
    nt_store_f2(v[6] - lse, v[7] - lse, o + 6);
  } else {
    nt_store_f2(v[8] - lse, v[9] - lse, o + 8);
  }
}

extern "C" void kernel_launch(void* const* d_in, const int* in_sizes, int n_in,
                              void* d_out, int out_size, void* d_ws, size_t ws_size,
                              hipStream_t stream) {
  const float* x  = (const float*)d_in[0];
  const int*   ei = (const int*)d_in[1];
  const float* W1 = (const float*)d_in[2];
  const float* b1 = (const float*)d_in[3];
  const float* W2 = (const float*)d_in[4];
  const float* b2 = (const float*)d_in[5];
  float* out = (float*)d_out;
  int E = in_sizes[1] / 2;
  const int* src = ei;
  const int* dst = ei + E;

  char* p = (char*)d_ws;
  auto alloc = [&](size_t bytes) {
    char* r = p;
    p += (bytes + 255) & ~(size_t)255;
    return r;
  };
  size_t tabsz = (size_t)NN * 8 * 4;  // 3.2 MB ([N][16] fp16 = [N][8] uints)
  float* dinv        = (float*)alloc((size_t)NN * 4);
  int*   row_start   = (int*)alloc((size_t)(NN + 1) * 4);
  int*   bucket_cnt  = (int*)alloc((size_t)NBUCK * 4);
  int*   bucket_base = (int*)alloc((size_t)(NBUCK + 1) * 4);
  int*   bucket_cur  = (int*)alloc((size_t)NBUCK * 4);
  int*   col         = (int*)alloc((size_t)E * 4);
  // regionA: packed (E ints, 12.8 MB) dead after k_bucket; tab1+tab2 (6.4 MB) overlay it.
  size_t needA = tabsz * 2;
  size_t regA = (size_t)E * 4;
  char*  A = (char*)alloc(regA > needA ? regA : needA);
  int*      packed = (int*)A;
  unsigned* tab1 = (unsigned*)A;
  unsigned* tab2 = (unsigned*)(A + tabsz);

  int nblk4N = (4 * NN + 255) / 256;    // 1563
  int nblk_place = (E + TILE - 1) / TILE;
  hipLaunchKernelGGL(k_zero, dim3(2), dim3(256), 0, stream, bucket_cnt);
  hipLaunchKernelGGL(k_bincount, dim3(1024), dim3(256), 0, stream, dst, E, bucket_cnt);
  hipLaunchKernelGGL(k_binscan, dim3(1), dim3(512), 0, stream, bucket_cnt, bucket_base, bucket_cur);
  hipLaunchKernelGGL(k_binplace, dim3(nblk_place), dim3(BPT), 0, stream, src, dst, E, bucket_cur, packed);
  hipLaunchKernelGGL(k_bucket, dim3(NBUCK), dim3(256), 0, stream, packed, bucket_base, row_start, dinv, col, E);
  hipLaunchKernelGGL(k_lin1, dim3((NN / 4 + 255) / 256), dim3(256), 0, stream, x, W1, dinv, tab1);
  hipLaunchKernelGGL(k_agg1, dim3(nblk4N), dim3(256), 0, stream,
                     (const uint4*)tab1, row_start, col, dinv, b1, W2, tab2);
  hipLaunchKernelGGL(k_agg2, dim3(nblk4N), dim3(256), 0, stream, tab2, row_start, col, dinv, b2, out);
}

// Round 9
// 195.692 us; speedup vs baseline: 2.3519x; 1.0943x over previous
//
#include <hip/hip_runtime.h>
#include <hip/hip_fp16.h>
#include <math.h>

#define NN 100000
#define F0 128
#define F1 16
#define F2 10
#define NBUCK 391   // ceil(NN / 256)
#define TILE 8192   // edges per binplace block (32KB stage)
#define EPT 16      // edges per thread in binplace (TILE / BPT)
#define CAP 16384   // LDS staging capacity in k_bucket
#define BPT 512     // binplace threads

__device__ inline void fma4(float4& a, float s, const float4& w) {
  a.x = fmaf(s, w.x, a.x);
  a.y = fmaf(s, w.y, a.y);
  a.z = fmaf(s, w.z, a.z);
  a.w = fmaf(s, w.w, a.w);
}

__device__ inline unsigned pk2(float a, float b) {
  __half ha = __float2half(a), hb = __float2half(b);
  return (unsigned)__half_as_ushort(ha) | ((unsigned)__half_as_ushort(hb) << 16);
}

__device__ inline float2 up2(unsigned u) {
  __half2 h;
  *(unsigned*)&h = u;
  return __half22float2(h);
}

__device__ inline void nt_store_f2(float a, float b, float* p) {
  union { double d; float f[2]; } u;
  u.f[0] = a; u.f[1] = b;
  __builtin_nontemporal_store(u.d, (double*)p);
}

// ==================== CSR build (two-level counting sort) ====================
__global__ void k_zero(int* __restrict__ bucket_cnt) {
  int i = blockIdx.x * blockDim.x + threadIdx.x;
  if (i < NBUCK) bucket_cnt[i] = 0;
}

__global__ __launch_bounds__(256) void k_bincount(const int* __restrict__ dst, int E,
                                                  int* __restrict__ bucket_cnt) {
  __shared__ int hist[NBUCK];
  int t = threadIdx.x;
  for (int i = t; i < NBUCK; i += 256) hist[i] = 0;
  __syncthreads();
  int per = (E + gridDim.x - 1) / gridDim.x;
  int e0 = blockIdx.x * per, e1 = min(E, e0 + per);
  for (int e = e0 + t; e < e1; e += 256)
    atomicAdd(&hist[__builtin_nontemporal_load(dst + e) >> 8], 1);
  __syncthreads();
  for (int i = t; i < NBUCK; i += 256)
    if (hist[i]) atomicAdd(&bucket_cnt[i], hist[i]);
}

__global__ void k_binscan(const int* __restrict__ bucket_cnt, int* __restrict__ bucket_base,
                          int* __restrict__ bucket_cur) {
  __shared__ int lds[512];
  int t = threadIdx.x;
  int v = (t < NBUCK) ? bucket_cnt[t] : 0;
  lds[t] = v;
  __syncthreads();
  for (int o = 1; o < 512; o <<= 1) {
    int add = (t >= o) ? lds[t - o] : 0;
    __syncthreads();
    lds[t] += add;
    __syncthreads();
  }
  if (t < NBUCK) {
    int excl = lds[t] - v;
    bucket_base[t] = excl;
    bucket_cur[t] = excl;
    if (t == NBUCK - 1) bucket_base[NBUCK] = lds[t];  // == E
  }
}

// LDS-reorder binplace with remembered-position scatter:
// phase A: ONE LDS atomic per edge (histogram, returned pos kept in VGPRs)
// phase B: atomic-free LDS scatter at loff[bk]+pos
// copy-out: 16-lane sub-groups per bucket run.
__global__ __launch_bounds__(BPT) void k_binplace(const int* __restrict__ src,
                                                  const int* __restrict__ dst, int E,
                                                  int* __restrict__ bucket_cur,
                                                  int* __restrict__ packed) {
  __shared__ int cnt[NBUCK];    // per-bucket counts (preserved)
  __shared__ int loff[NBUCK];   // local exclusive offsets
  __shared__ int gbase[NBUCK];  // global base of this block's run per bucket
  __shared__ int part[256];     // scan partials
  __shared__ int stage[TILE];   // 32 KB reorder buffer
  int t = threadIdx.x;
  int e0 = blockIdx.x * TILE, e1 = min(E, e0 + TILE);
  int total = e1 - e0;
  for (int i = t; i < NBUCK; i += BPT) cnt[i] = 0;
  __syncthreads();
  // phase A: histogram with remembered positions (pos < 8192 -> 13 bits; bk < 391 -> 9 bits)
  int bkpos[EPT];
  int pval[EPT];
#pragma unroll
  for (int k = 0; k < EPT; k++) {
    int e = e0 + t + k * BPT;
    if (e < e1) {
      int d = __builtin_nontemporal_load(dst + e);
      int s = __builtin_nontemporal_load(src + e);
      int bk = d >> 8;
      int pos = atomicAdd(&cnt[bk], 1);
      bkpos[k] = (bk << 13) | pos;
      pval[k] = (s << 8) | (d & 255);
    } else {
      bkpos[k] = -1;
    }
  }
  __syncthreads();
  // reserve global space per bucket
  for (int i = t; i < NBUCK; i += BPT) {
    int c = cnt[i];
    gbase[i] = c ? atomicAdd(&bucket_cur[i], c) : 0;
  }
  // block scan of cnt -> loff (256 owners x 2 entries)
  if (t < 256) {
    int i0 = 2 * t, i1 = 2 * t + 1;
    int c0 = (i0 < NBUCK) ? cnt[i0] : 0;
    int c1 = (i1 < NBUCK) ? cnt[i1] : 0;
    part[t] = c0 + c1;
  }
  __syncthreads();
  for (int o = 1; o < 256; o <<= 1) {
    int add = 0;
    if (t < 256 && t >= o) add = part[t - o];
    __syncthreads();
    if (t < 256) part[t] += add;
    __syncthreads();
  }
  if (t < 256) {
    int i0 = 2 * t, i1 = 2 * t + 1;
    int c0 = (i0 < NBUCK) ? cnt[i0] : 0;
    int c1 = (i1 < NBUCK) ? cnt[i1] : 0;
    int excl = part[t] - c0 - c1;
    if (i0 < NBUCK) loff[i0] = excl;
    if (i1 < NBUCK) loff[i1] = excl + c0;
  }
  __syncthreads();
  // phase B: atomic-free LDS scatter
#pragma unroll
  for (int k = 0; k < EPT; k++) {
    if (bkpos[k] >= 0) {
      int bk = bkpos[k] >> 13, pos = bkpos[k] & 8191;
      stage[loff[bk] + pos] = pval[k];
    }
  }
  __syncthreads();
  // contiguous run copy: 16-lane sub-group per bucket stripe
  int sub = t >> 4, lane = t & 15;  // 32 sub-groups
  for (int bk = sub; bk < NBUCK; bk += BPT / 16) {
    int lo = loff[bk];
    int hi = (bk + 1 < NBUCK) ? loff[bk + 1] : total;
    int gb = gbase[bk];
    for (int i = lo + lane; i < hi; i += 16) packed[gb + (i - lo)] = stage[i];
  }
}

__global__ __launch_bounds__(256) void k_bucket(const int* __restrict__ packed,
                                                const int* __restrict__ bucket_base,
                                                int* __restrict__ row_start,
                                                float* __restrict__ dinv,
                                                int* __restrict__ col, int E) {
  __shared__ int stage[CAP];
  __shared__ int hist[256];
  __shared__ int off[256];
  __shared__ int cur[256];
  int b = blockIdx.x, t = threadIdx.x;
  int base = bucket_base[b];
  int cnt = bucket_base[b + 1] - base;
  hist[t] = 0;
  bool staged = (cnt <= CAP);
  if (staged)
    for (int i = t; i < cnt; i += 256) stage[i] = __builtin_nontemporal_load(packed + base + i);
  __syncthreads();
  if (staged) {
    for (int i = t; i < cnt; i += 256) atomicAdd(&hist[stage[i] & 255], 1);
  } else {
    for (int i = t; i < cnt; i += 256) atomicAdd(&hist[packed[base + i] & 255], 1);
  }
  __syncthreads();
  int v = hist[t];
  off[t] = v;
  __syncthreads();
  for (int o = 1; o < 256; o <<= 1) {
    int add = (t >= o) ? off[t - o] : 0;
    __syncthreads();
    off[t] += add;
    __syncthreads();
  }
  int excl = off[t] - v;
  cur[t] = excl;
  int d = b * 256 + t;
  if (d < NN) {
    row_start[d] = base + excl;
    dinv[d] = rsqrtf((float)(v + 1));  // +1 self-loop
  }
  if (b == 0 && t == 0) row_start[NN] = E;
  __syncthreads();
  if (staged) {
    for (int i = t; i < cnt; i += 256) {
      int p = stage[i];
      int pos = atomicAdd(&cur[p & 255], 1);
      col[base + pos] = p >> 8;
    }
  } else {
    for (int i = t; i < cnt; i += 256) {
      int p = packed[base + i];
      int pos = atomicAdd(&cur[p & 255], 1);
      col[base + pos] = p >> 8;
    }
  }
}

// ==================== tab1 = fp16(dinv * (x @ W1)), [N][16] fp16 (3.2 MB) ====================
__global__ __launch_bounds__(256) void k_lin1(const float* __restrict__ x,
                                              const float* __restrict__ W1,
                                              const float* __restrict__ dinv,
                                              unsigned* __restrict__ tab1) {
  __shared__ float4 wl[F0 * 4];  // [k][jq], 8 KB
  int t = threadIdx.x;
  for (int i = t; i < F0 * 4; i += 256) wl[i] = ((const float4*)W1)[i];
  __syncthreads();
  int row0 = (blockIdx.x * 256 + t) * 4;
  if (row0 >= NN) return;  // N % 4 == 0
  float4 acc[4][4];
#pragma unroll
  for (int r = 0; r < 4; r++)
#pragma unroll
    for (int j = 0; j < 4; j++) acc[r][j] = make_float4(0.f, 0.f, 0.f, 0.f);
  const float4* xr0 = (const float4*)(x + (size_t)(row0 + 0) * F0);
  const float4* xr1 = (const float4*)(x + (size_t)(row0 + 1) * F0);
  const float4* xr2 = (const float4*)(x + (size_t)(row0 + 2) * F0);
  const float4* xr3 = (const float4*)(x + (size_t)(row0 + 3) * F0);
  for (int k4 = 0; k4 < F0 / 4; k4++) {
    float4 xv[4];
    xv[0] = xr0[k4]; xv[1] = xr1[k4]; xv[2] = xr2[k4]; xv[3] = xr3[k4];
#pragma unroll
    for (int kk = 0; kk < 4; kk++) {
      float4 w0 = wl[(k4 * 4 + kk) * 4 + 0];
      float4 w1 = wl[(k4 * 4 + kk) * 4 + 1];
      float4 w2 = wl[(k4 * 4 + kk) * 4 + 2];
      float4 w3 = wl[(k4 * 4 + kk) * 4 + 3];
#pragma unroll
      for (int r = 0; r < 4; r++) {
        float xs = kk == 0 ? xv[r].x : kk == 1 ? xv[r].y : kk == 2 ? xv[r].z : xv[r].w;
        fma4(acc[r][0], xs, w0);
        fma4(acc[r][1], xs, w1);
        fma4(acc[r][2], xs, w2);
        fma4(acc[r][3], xs, w3);
      }
    }
  }
#pragma unroll
  for (int r = 0; r < 4; r++) {
    float dd = dinv[row0 + r];
    float4 a0 = acc[r][0], a1 = acc[r][1], a2 = acc[r][2], a3 = acc[r][3];
    uint4 o0, o1;
    o0.x = pk2(dd * a0.x, dd * a0.y);
    o0.y = pk2(dd * a0.z, dd * a0.w);
    o0.z = pk2(dd * a1.x, dd * a1.y);
    o0.w = pk2(dd * a1.z, dd * a1.w);
    o1.x = pk2(dd * a2.x, dd * a2.y);
    o1.y = pk2(dd * a2.z, dd * a2.w);
    o1.z = pk2(dd * a3.x, dd * a3.y);
    o1.w = pk2(dd * a3.z, dd * a3.w);
    uint4* orow = (uint4*)(tab1 + (size_t)(row0 + r) * 8);
    orow[0] = o0;
    orow[1] = o1;
  }
}

// ==================== agg1 (+bias+ReLU) fused with lin2; 4-thread quad per dst ====================
__global__ __launch_bounds__(256) void k_agg1(const uint4* __restrict__ tab1,
                                              const int* __restrict__ row_start,
                                              const int* __restrict__ col,
                                              const float* __restrict__ dinv,
                                              const float* __restrict__ b1,
                                              const float* __restrict__ W2g,
                                              unsigned* __restrict__ tab2) {
  __shared__ float w2[F1][F2];
  __shared__ float b1l[F1];
  int t = threadIdx.x;
  if (t < F1 * F2) w2[t / F2][t % F2] = W2g[t];
  if (t < F1) b1l[t] = b1[t];
  __syncthreads();
  int g = blockIdx.x * 256 + t;
  int d = g >> 2, q = g & 3;
  if (d >= NN) return;
  float a[16];
#pragma unroll
  for (int j = 0; j < 16; j++) a[j] = 0.f;
  auto addrow = [&](int s) {
    uint4 v0 = tab1[2 * s];
    uint4 v1 = tab1[2 * s + 1];
    float2 f;
    f = up2(v0.x); a[0] += f.x; a[1] += f.y;
    f = up2(v0.y); a[2] += f.x; a[3] += f.y;
    f = up2(v0.z); a[4] += f.x; a[5] += f.y;
    f = up2(v0.w); a[6] += f.x; a[7] += f.y;
    f = up2(v1.x); a[8] += f.x; a[9] += f.y;
    f = up2(v1.y); a[10] += f.x; a[11] += f.y;
    f = up2(v1.z); a[12] += f.x; a[13] += f.y;
    f = up2(v1.w); a[14] += f.x; a[15] += f.y;
  };
  if (q == 0) addrow(d);  // self-loop row
  int e = row_start[d] + q, e1 = row_start[d + 1];
  for (; e + 4 < e1; e += 8) {
    int s0 = __builtin_nontemporal_load(col + e);
    int s1 = __builtin_nontemporal_load(col + e + 4);
    addrow(s0);
    addrow(s1);
  }
  if (e < e1) addrow(__builtin_nontemporal_load(col + e));
#pragma unroll
  for (int j = 0; j < 16; j++) a[j] += __shfl_xor(a[j], 1);
#pragma unroll
  for (int j = 0; j < 16; j++) a[j] += __shfl_xor(a[j], 2);
  if (q >= 2) return;
  float dd = dinv[d];
  float h[16];
#pragma unroll
  for (int j = 0; j < 16; j++) h[j] = fmaxf(fmaf(dd, a[j], b1l[j]), 0.f);
  if (q == 0) {
    float p[8];
#pragma unroll
    for (int j = 0; j < 8; j++) {
      float s = 0.f;
#pragma unroll
      for (int kk = 0; kk < 16; kk++) s = fmaf(h[kk], w2[kk][j], s);
      p[j] = s;
    }
    uint4 o;
    o.x = pk2(dd * p[0], dd * p[1]);
    o.y = pk2(dd * p[2], dd * p[3]);
    o.z = pk2(dd * p[4], dd * p[5]);
    o.w = pk2(dd * p[6], dd * p[7]);
    *(uint4*)(tab2 + (size_t)d * 8) = o;
  } else {
    float p8 = 0.f, p9 = 0.f;
#pragma unroll
    for (int kk = 0; kk < 16; kk++) {
      p8 = fmaf(h[kk], w2[kk][8], p8);
      p9 = fmaf(h[kk], w2[kk][9], p9);
    }
    tab2[(size_t)d * 8 + 4] = pk2(dd * p8, dd * p9);
  }
}

// ==================== agg2 + bias + log_softmax; 4-thread quad per dst ====================
__global__ __launch_bounds__(256) void k_agg2(const unsigned* __restrict__ tab2,
                                              const int* __restrict__ row_start,
                                              const int* __restrict__ col,
                                              const float* __restrict__ dinv,
                                              const float* __restrict__ b2,
                                              float* __restrict__ out) {
  __shared__ float b2l[F2];
  int t = threadIdx.x;
  if (t < F2) b2l[t] = b2[t];
  __syncthreads();
  int g = blockIdx.x * 256 + t;
  int d = g >> 2, q = g & 3;
  if (d >= NN) return;
  float a[10];
#pragma unroll
  for (int j = 0; j < 10; j++) a[j] = 0.f;
  auto addrow = [&](int s) {
    uint4 v = *(const uint4*)(tab2 + (size_t)s * 8);
    unsigned w = tab2[(size_t)s * 8 + 4];
    float2 f;
    f = up2(v.x); a[0] += f.x; a[1] += f.y;
    f = up2(v.y); a[2] += f.x; a[3] += f.y;
    f = up2(v.z); a[4] += f.x; a[5] += f.y;
    f = up2(v.w); a[6] += f.x; a[7] += f.y;
    f = up2(w);   a[8] += f.x; a[9] += f.y;
  };
  if (q == 0) addrow(d);  // self-loop
  int e = row_start[d] + q, e1 = row_start[d + 1];
  for (; e + 4 < e1; e += 8) {
    int s0 = __builtin_nontemporal_load(col + e);
    int s1 = __builtin_nontemporal_load(col + e + 4);
    addrow(s0);
    addrow(s1);
  }
  if (e < e1) addrow(__builtin_nontemporal_load(col + e));
#pragma unroll
  for (int j = 0; j < 10; j++) a[j] += __shfl_xor(a[j], 1);
#pragma unroll
  for (int j = 0; j < 10; j++) a[j] += __shfl_xor(a[j], 2);
  if (q >= 3) return;
  float dd = dinv[d];
  float v[10];
#pragma unroll
  for (int j = 0; j < F2; j++) v[j] = fmaf(dd, a[j], b2l[j]);
  float m = v[0];
#pragma unroll
  for (int j = 1; j < F2; j++) m = fmaxf(m, v[j]);
  float sum = 0.f;
#pragma unroll
  for (int j = 0; j < F2; j++) sum += expf(v[j] - m);
  float lse = m + logf(sum);
  float* o = out + (size_t)d * F2;  // rows are 40 B -> 8 B aligned
  if (q == 0) {
    nt_store_f2(v[0] - lse, v[1] - lse, o + 0);
    nt_store_f2(v[2] - lse, v[3] - lse, o + 2);
  } else if (q == 1) {
    nt_store_f2(v[4] - lse, v[5] - lse, o + 4);
    nt_store_f2(v[6] - lse, v[7] - lse, o + 6);
  } else {
    nt_store_f2(v[8] - lse, v[9] - lse, o + 8);
  }
}

extern "C" void kernel_launch(void* const* d_in, const int* in_sizes, int n_in,
                              void* d_out, int out_size, void* d_ws, size_t ws_size,
                              hipStream_t stream) {
  const float* x  = (const float*)d_in[0];
  const int*   ei = (const int*)d_in[1];
  const float* W1 = (const float*)d_in[2];
  const float* b1 = (const float*)d_in[3];
  const float* W2 = (const float*)d_in[4];
  const float* b2 = (const float*)d_in[5];
  float* out = (float*)d_out;
  int E = in_sizes[1] / 2;
  const int* src = ei;
  const int* dst = ei + E;

  char* p = (char*)d_ws;
  auto alloc = [&](size_t bytes) {
    char* r = p;
    p += (bytes + 255) & ~(size_t)255;
    return r;
  };
  size_t tabsz = (size_t)NN * 8 * 4;  // 3.2 MB ([N][16] fp16 = [N][8] uints)
  float* dinv        = (float*)alloc((size_t)NN * 4);
  int*   row_start   = (int*)alloc((size_t)(NN + 1) * 4);
  int*   bucket_cnt  = (int*)alloc((size_t)NBUCK * 4);
  int*   bucket_base = (int*)alloc((size_t)(NBUCK + 1) * 4);
  int*   bucket_cur  = (int*)alloc((size_t)NBUCK * 4);
  int*   col         = (int*)alloc((size_t)E * 4);
  // regionA: packed (E ints, 12.8 MB) dead after k_bucket; tab1+tab2 (6.4 MB) overlay it.
  size_t needA = tabsz * 2;
  size_t regA = (size_t)E * 4;
  char*  A = (char*)alloc(regA > needA ? regA : needA);
  int*      packed = (int*)A;
  unsigned* tab1 = (unsigned*)A;
  unsigned* tab2 = (unsigned*)(A + tabsz);

  int nblk4N = (4 * NN + 255) / 256;    // 1563
  int nblk_place = (E + TILE - 1) / TILE;
  hipLaunchKernelGGL(k_zero, dim3(2), dim3(256), 0, stream, bucket_cnt);
  hipLaunchKernelGGL(k_bincount, dim3(1024), dim3(256), 0, stream, dst, E, bucket_cnt);
  hipLaunchKernelGGL(k_binscan, dim3(1), dim3(512), 0, stream, bucket_cnt, bucket_base, bucket_cur);
  hipLaunchKernelGGL(k_binplace, dim3(nblk_place), dim3(BPT), 0, stream, src, dst, E, bucket_cur, packed);
  hipLaunchKernelGGL(k_bucket, dim3(NBUCK), dim3(256), 0, stream, packed, bucket_base, row_start, dinv, col, E);
  hipLaunchKernelGGL(k_lin1, dim3((NN / 4 + 255) / 256), dim3(256), 0, stream, x, W1, dinv, tab1);
  hipLaunchKernelGGL(k_agg1, dim3(nblk4N), dim3(256), 0, stream,
                     (const uint4*)tab1, row_start, col, dinv, b1, W2, tab2);
  hipLaunchKernelGGL(k_agg2, dim3(nblk4N), dim3(256), 0, stream, tab2, row_start, col, dinv, b2, out);
}